// Round 11
// baseline (433.442 us; speedup 1.0000x reference)
//
#include <hip/hip_runtime.h>
#include <hip/hip_bf16.h>

// ---------------------------------------------------------------------------
// Net_19378892440061: ContinuousConv fluid network, Round 11.
// Changes vs Round 10:
//  - Layers 2/3 run as a pipelined fused kernel: one dispatch contains gemm
//    blocks (chunk c-1) + abuild blocks (chunk c), ping-pong A buffers,
//    4 chunks of 4000 rows. Write-BW-bound abuild overlaps read/MFMA-bound
//    gemm (round 10: serialized 105 + 45 us). No intra-dispatch dependency:
//    gemm reads A written by the PREVIOUS dispatch.
//  - abuild restructured to 4 waves/block with CIN-halved FW (per-wave LDS
//    16.1 KB; block 64.5 KB dynamic, shared carve with gemm's 30.7 KB).
//  - Cpart is full-M; one reduce per layer.
// ---------------------------------------------------------------------------

#define M_FLUID 16000
#define KNBR 64

typedef __attribute__((ext_vector_type(8))) short bf16x8;
typedef __attribute__((ext_vector_type(4))) float f32x4;
typedef __attribute__((ext_vector_type(4))) unsigned short u16x4;

__device__ __forceinline__ ushort f2bf(float f) {
    __hip_bfloat16 h = __float2bfloat16(f);   // RNE
    return *(ushort*)&h;
}

__device__ __forceinline__ float sgnf(float v) {
    return (v > 0.f) ? 1.f : ((v < 0.f) ? -1.f : 0.f);
}

// Volume-preserving ball->cube map (matches reference _ball_to_cube, fp32).
__device__ __forceinline__ void ball_to_cube(float x, float y, float z,
                                             float& xc, float& yc, float& zc) {
    const float eps = 1e-12f;
    float sq  = x*x + y*y + z*z;
    float nrm = sqrtf(fmaxf(sq, eps));
    float rho = sqrtf(fmaxf(x*x + y*y, eps));
    bool  top = (1.25f*z*z > x*x + y*y);
    float s_top = sqrtf(3.0f*nrm/(nrm + fabsf(z)));
    float xs = top ? x*s_top : x*nrm/rho;
    float ys = top ? y*s_top : y*nrm/rho;
    float zs = top ? sgnf(z)*nrm : 1.5f*z;
    if (sq < eps) { xs = 0.f; ys = 0.f; zs = 0.f; }
    float rxy = sqrtf(fmaxf(xs*xs + ys*ys, eps));
    bool use_x = fabsf(ys) <= fabsf(xs);
    float dx = (use_x && fabsf(xs) > eps) ? xs : 1.0f;
    float dy = (!use_x && fabsf(ys) > eps) ? ys : 1.0f;
    const float c4pi = 1.2732395447351628f;  // 4/pi
    float xc_, yc_;
    if (use_x) {
        xc_ = sgnf(xs)*rxy;
        yc_ = sgnf(xs)*rxy*c4pi*atanf(ys/dx);
    } else {
        xc_ = sgnf(ys)*rxy*c4pi*atanf(xs/dy);
        yc_ = sgnf(ys)*rxy;
    }
    if (xs*xs + ys*ys < eps) { xc_ = 0.f; yc_ = 0.f; }
    xc = xc_; yc = yc_; zc = zs;
}

// Per-pair geometry for BOTH neighbor lists (blockIdx.y: 0=fluid, 1=wall).
__global__ void geom_dual_kernel(const float* __restrict__ fluid_pos,
                                 const float* __restrict__ wall_pos,
                                 const int*  __restrict__ nbrF,
                                 const int*  __restrict__ nbrW,
                                 float4* __restrict__ gFf, int* __restrict__ gIf,
                                 float4* __restrict__ gFw, int* __restrict__ gIw,
                                 int M) {
    int t = blockIdx.x * blockDim.x + threadIdx.x;
    if (t >= M * KNBR) return;
    const float* pos_in; const int* nbr; float4* geomF; int* geomI; int excl_self;
    if (blockIdx.y == 0) { pos_in = fluid_pos; nbr = nbrF; geomF = gFf; geomI = gIf; excl_self = 1; }
    else                 { pos_in = wall_pos;  nbr = nbrW; geomF = gFw; geomI = gIw; excl_self = 0; }
    int n = t >> 6;
    int k = t & 63;
    int j = nbr[t];
    float px = fluid_pos[n*3+0], py = fluid_pos[n*3+1], pz = fluid_pos[n*3+2];
    float qx = pos_in[(size_t)j*3+0], qy = pos_in[(size_t)j*3+1], qz = pos_in[(size_t)j*3+2];
    float dx = qx - px, dy = qy - py, dz = qz - pz;

    bool valid;
    if (k == 0) {
        // reproduce numpy fp32 distance exactly (no FMA contraction)
#pragma clang fp contract(off)
        float d2f = dx*dx + dy*dy;
        d2f = d2f + dz*dz;
        double d2 = (double)d2f;
        const double RADIUS_D = 0.5*(6.0*1.5*0.025);  // 0.1125
        valid = d2 < RADIUS_D*RADIUS_D;
        if (excl_self) valid = valid && (d2 > 1e-18);
    } else {
        valid = (j != 0);  // ascending neighbor ids: 0 past slot 0 == padding
    }

    const float Rf = (float)(0.5*(6.0*1.5*0.025));
    float ux = dx / Rf, uy = dy / Rf, uz = dz / Rf;
    float r2 = ux*ux + uy*uy; r2 += uz*uz;
    float w1 = 1.f - r2;
    float win = fminf(fmaxf(w1*w1*w1, 0.f), 1.f);

    float bx, by, bz;
    ball_to_cube(ux, uy, uz, bx, by, bz);
    float cx = fminf(fmaxf((bx*0.5f + 0.5f)*3.f, 0.f), 3.f);
    float cy = fminf(fmaxf((by*0.5f + 0.5f)*3.f, 0.f), 3.f);
    float cz = fminf(fmaxf((bz*0.5f + 0.5f)*3.f, 0.f), 3.f);
    float ix = fminf(fmaxf(floorf(cx), 0.f), 2.f);
    float iy = fminf(fmaxf(floorf(cy), 0.f), 2.f);
    float iz = fminf(fmaxf(floorf(cz), 0.f), 2.f);
    float fx = cx - ix, fy = cy - iy, fz = cz - iz;
    int cell = ((int)ix*4 + (int)iy)*4 + (int)iz;

    geomF[t] = make_float4(valid ? win : 0.f, fx, fy, fz);
    geomI[t] = cell;
}

// ---- abuild body (fused kernel): 4 waves/block, wave = one particle,
// CIN processed in two halves (FW buffer = CIN/2 rows). Same A output layout.
template<int CIN>
__device__ __forceinline__ void abuild_body(char* smem, int blk,
        const float* __restrict__ feat, const int* __restrict__ nbr,
        const float4* __restrict__ geomF, const int* __restrict__ geomI,
        const float* __restrict__ dense, ushort* __restrict__ A,
        int m0, int m1, int Ktot) {
    constexpr int H = CIN / 2;          // 48 (cin96) or 32 (cin64)
    constexpr int NTH = H / 16;         // 3 or 2
    constexpr int SP = 72;
    int w = threadIdx.x >> 6, l = threadIdx.x & 63;
    ushort* S  = (ushort*)(smem + (size_t)w * ((64 + H) * SP * 2));
    ushort* FW = S + 64*SP;
    int n = m0 + blk*4 + w;
    if (n >= m1) return;

    {   // zero S
        uint4 z = make_uint4(0,0,0,0);
        uint4* Sv = (uint4*)S;
#pragma unroll
        for (int i = 0; i < 9; ++i) Sv[l + 64*i] = z;
    }
    size_t t = (size_t)n * KNBR + l;
    float4 g = geomF[t];
    int cell = geomI[t];
    int j = nbr[t];
    {
        float win = g.x;
        float x1 = g.y, y1 = g.z, z1 = g.w;
        float x0 = 1.f-x1, y0 = 1.f-y1, z0 = 1.f-z1;
        float w00 = y0*z0*win, w01 = y0*z1*win, w10 = y1*z0*win, w11 = y1*z1*win;
        ushort* Sc = S + cell*SP + l;
        Sc[0*SP]  = f2bf(x0*w00);
        Sc[1*SP]  = f2bf(x0*w01);
        Sc[4*SP]  = f2bf(x0*w10);
        Sc[5*SP]  = f2bf(x0*w11);
        Sc[16*SP] = f2bf(x1*w00);
        Sc[17*SP] = f2bf(x1*w01);
        Sc[20*SP] = f2bf(x1*w10);
        Sc[21*SP] = f2bf(x1*w11);
    }
    int lm = l & 15, koct = l >> 4;
    const float* frow = feat + (size_t)j * CIN;
    ushort* Arow = A + (size_t)(n - m0) * Ktot;
#pragma unroll
    for (int h = 0; h < 2; ++h) {
        // FW gather for channels [h*H, h*H+H)
#pragma unroll
        for (int c4 = 0; c4 < H; c4 += 4) {
            float4 v = *(const float4*)(frow + h*H + c4);
            FW[(c4+0)*SP + l] = f2bf(v.x);
            FW[(c4+1)*SP + l] = f2bf(v.y);
            FW[(c4+2)*SP + l] = f2bf(v.z);
            FW[(c4+3)*SP + l] = f2bf(v.w);
        }
        f32x4 acc[4][NTH];
#pragma unroll
        for (int mt = 0; mt < 4; ++mt)
#pragma unroll
            for (int nt = 0; nt < NTH; ++nt)
                acc[mt][nt] = (f32x4){0.f,0.f,0.f,0.f};
#pragma unroll
        for (int ks = 0; ks < 2; ++ks) {
            bf16x8 sf[4];
#pragma unroll
            for (int mt = 0; mt < 4; ++mt)
                sf[mt] = *(const bf16x8*)&S[(mt*16 + lm)*SP + ks*32 + koct*8];
#pragma unroll
            for (int nt = 0; nt < NTH; ++nt) {
                bf16x8 ff = *(const bf16x8*)&FW[(nt*16 + lm)*SP + ks*32 + koct*8];
#pragma unroll
                for (int mt = 0; mt < 4; ++mt)
                    acc[mt][nt] = __builtin_amdgcn_mfma_f32_16x16x32_bf16(
                                      sf[mt], ff, acc[mt][nt], 0, 0, 0);
            }
        }
        // C/D: col(=ch)=lm, row(=cell)=koct*4+r (+16*mt) -> AT[ch][cell] (=FW)
        ushort* AT = FW;
#pragma unroll
        for (int nt = 0; nt < NTH; ++nt)
#pragma unroll
            for (int mt = 0; mt < 4; ++mt) {
                u16x4 pk;
                pk.x = f2bf(acc[mt][nt][0]);
                pk.y = f2bf(acc[mt][nt][1]);
                pk.z = f2bf(acc[mt][nt][2]);
                pk.w = f2bf(acc[mt][nt][3]);
                *(u16x4*)&AT[(nt*16 + lm)*SP + mt*16 + koct*4] = pk;
            }
        // coalesced writeback, k' = (h*H+ch)*64 + cell
#pragma unroll
        for (int it = 0; it < H/8; ++it) {
            int i = l + 64*it;
            int ch = i >> 3, cc = (i & 7) * 8;
            *(uint4*)&Arow[(h*H + ch)*64 + cc] = *(const uint4*)&AT[ch*SP + cc];
        }
    }
    // dense tail
#pragma unroll
    for (int c0 = 0; c0 < CIN; c0 += 64) {
        int ch = c0 + l;
        if (ch < CIN) Arow[64*CIN + ch] = f2bf(dense[(size_t)n*CIN + ch]);
    }
}

// ---- gemm body (fused kernel): round-7 gemm7 with dynamic-LDS carve and
// full-M Cpart (slab stride Mtot*64, rows at global offset gm0).
__device__ __forceinline__ void gemm_body(char* smem, int gblk,
        const ushort* __restrict__ A, int Ktot, const ushort* __restrict__ Wt,
        float* __restrict__ Cpart, int rows, int gm0, int nks, int KS, int Mtot) {
    constexpr int SP = 40;
    ushort* Ash = (ushort*)smem;            // [2][128][SP]
    ushort* Bsh = Ash + 2*128*SP;           // [2][64][SP]
    int tid = threadIdx.x;
    int w = tid >> 6, l = tid & 63;
    int lm = l & 15, koct = l >> 4;
    int mb = gblk / KS;
    int ksy = gblk - mb*KS;
    int per = (nks + KS - 1) / KS;
    int ksa = ksy * per;
    int ksb = ksa + per; if (ksb > nks) ksb = nks;
    int nk = ksb - ksa;

    f32x4 acc[2][4];
#pragma unroll
    for (int fi = 0; fi < 2; ++fi)
#pragma unroll
        for (int nt = 0; nt < 4; ++nt) acc[fi][nt] = (f32x4){0.f,0.f,0.f,0.f};

    int rS  = tid >> 2;
    int kb4 = tid & 3;
    int rA0 = mb*128 + rS;       if (rA0 >= rows) rA0 = rows - 1;
    int rA1 = mb*128 + rS + 64;  if (rA1 >= rows) rA1 = rows - 1;

    bf16x8 ra0, ra1, rb;
    auto load_regs = [&](int ks) {
        int kk = ks*32 + kb4*8;
        ra0 = *(const bf16x8*)&A[(size_t)rA0*Ktot + kk];
        ra1 = *(const bf16x8*)&A[(size_t)rA1*Ktot + kk];
        rb  = *(const bf16x8*)&Wt[(size_t)rS*Ktot + kk];
    };
    auto store_lds = [&](int buf) {
        *(bf16x8*)&Ash[(buf*128 + rS)*SP + kb4*8]      = ra0;
        *(bf16x8*)&Ash[(buf*128 + rS + 64)*SP + kb4*8] = ra1;
        *(bf16x8*)&Bsh[(buf*64 + rS)*SP + kb4*8]       = rb;
    };

    if (nk > 0) {
        load_regs(ksa);
        store_lds(0);
        __syncthreads();
        for (int i = 0; i < nk; ++i) {
            int buf = i & 1;
            bool nxt = (i + 1 < nk);
            if (nxt) load_regs(ksa + i + 1);
            bf16x8 a0 = *(const bf16x8*)&Ash[(buf*128 + w*32 + lm)*SP + koct*8];
            bf16x8 a1 = *(const bf16x8*)&Ash[(buf*128 + w*32 + 16 + lm)*SP + koct*8];
#pragma unroll
            for (int nt = 0; nt < 4; ++nt) {
                bf16x8 b = *(const bf16x8*)&Bsh[(buf*64 + nt*16 + lm)*SP + koct*8];
                acc[0][nt] = __builtin_amdgcn_mfma_f32_16x16x32_bf16(a0, b, acc[0][nt], 0, 0, 0);
                acc[1][nt] = __builtin_amdgcn_mfma_f32_16x16x32_bf16(a1, b, acc[1][nt], 0, 0, 0);
            }
            if (nxt) {
                store_lds(buf ^ 1);
                __syncthreads();
            }
        }
    }

    float* Cp = Cpart + ((size_t)ksy * Mtot + gm0 + mb*128 + w*32) * 64;
    int gr0 = mb*128 + w*32;
#pragma unroll
    for (int fi = 0; fi < 2; ++fi)
#pragma unroll
        for (int nt = 0; nt < 4; ++nt)
#pragma unroll
            for (int r = 0; r < 4; ++r) {
                int row = fi*16 + koct*4 + r;
                if (gr0 + row < rows)
                    Cp[row * 64 + nt*16 + lm] = acc[fi][nt][r];
            }
}

// ---- fused pipeline stage: gemm blocks on chunk c-1 + abuild blocks on
// chunk c. No intra-dispatch dependency (gemm's A was written last dispatch).
template<int CIN>
__global__ __launch_bounds__(256) void fused_stage_kernel(
        const ushort* __restrict__ Ag, int Ktot, const ushort* __restrict__ Wt,
        float* __restrict__ Cpart, int grows, int ggm0, int nks, int KS,
        int Mtot, int G_gemm,
        const float* __restrict__ feat, const int* __restrict__ nbr,
        const float4* __restrict__ geomF, const int* __restrict__ geomI,
        const float* __restrict__ dense, ushort* __restrict__ Aa,
        int am0, int am1) {
    extern __shared__ char smem[];
    if ((int)blockIdx.x < G_gemm) {
        gemm_body(smem, blockIdx.x, Ag, Ktot, Wt, Cpart, grows, ggm0, nks, KS, Mtot);
    } else {
        abuild_body<CIN>(smem, blockIdx.x - G_gemm, feat, nbr, geomF, geomI,
                         dense, Aa, am0, am1, Ktot);
    }
}

// ---- MFMA-scatter abuild for CIN=3, BOTH L1 convs in one launch.
__global__ __launch_bounds__(64) void abuild_s3_dual_kernel(
        const float* __restrict__ featW, const float* __restrict__ featF,
        const int*   __restrict__ nbrW,  const int*   __restrict__ nbrF,
        const float4* __restrict__ gFw,  const int* __restrict__ gIw,
        const float4* __restrict__ gFf,  const int* __restrict__ gIf,
        ushort* __restrict__ A0, ushort* __restrict__ A1, int M) {
    constexpr int SP = 72;
    constexpr int Ktot = 192;
    __shared__ ushort S[64*SP];
    __shared__ ushort FW[16*SP];
    const float* feat; const int* nbr; const float4* geomF; const int* geomI; ushort* A;
    if (blockIdx.y == 0) { feat = featW; nbr = nbrW; geomF = gFw; geomI = gIw; A = A0; }
    else                 { feat = featF; nbr = nbrF; geomF = gFf; geomI = gIf; A = A1; }
    int l = threadIdx.x;
    int n = blockIdx.x;
    if (n >= M) return;

    {   // zero S (9 iters) + FW (144 uint4 units)
        uint4 z = make_uint4(0,0,0,0);
        uint4* Sv = (uint4*)S;
#pragma unroll
        for (int i = 0; i < 9; ++i) Sv[l + 64*i] = z;
        uint4* Fv = (uint4*)FW;
#pragma unroll
        for (int i = 0; i < 3; ++i) {
            int idx = l + 64*i;
            if (idx < (16*SP*2)/16) Fv[idx] = z;
        }
    }
    size_t t = (size_t)n * KNBR + l;
    float4 g = geomF[t];
    int cell = geomI[t];
    int j = nbr[t];
    {
        float win = g.x;
        float x1 = g.y, y1 = g.z, z1 = g.w;
        float x0 = 1.f-x1, y0 = 1.f-y1, z0 = 1.f-z1;
        float w00 = y0*z0*win, w01 = y0*z1*win, w10 = y1*z0*win, w11 = y1*z1*win;
        ushort* Sc = S + cell*SP + l;
        Sc[0*SP]  = f2bf(x0*w00);
        Sc[1*SP]  = f2bf(x0*w01);
        Sc[4*SP]  = f2bf(x0*w10);
        Sc[5*SP]  = f2bf(x0*w11);
        Sc[16*SP] = f2bf(x1*w00);
        Sc[17*SP] = f2bf(x1*w01);
        Sc[20*SP] = f2bf(x1*w10);
        Sc[21*SP] = f2bf(x1*w11);
    }
    {   // FW rows 0..2 = neighbor features
        const float* fr = feat + (size_t)j * 3;
        FW[0*SP + l] = f2bf(fr[0]);
        FW[1*SP + l] = f2bf(fr[1]);
        FW[2*SP + l] = f2bf(fr[2]);
    }
    int lm = l & 15, koct = l >> 4;
    f32x4 acc[4];
#pragma unroll
    for (int mt = 0; mt < 4; ++mt) acc[mt] = (f32x4){0.f,0.f,0.f,0.f};
#pragma unroll
    for (int ks = 0; ks < 2; ++ks) {
        bf16x8 ff = *(const bf16x8*)&FW[lm*SP + ks*32 + koct*8];
#pragma unroll
        for (int mt = 0; mt < 4; ++mt) {
            bf16x8 sf = *(const bf16x8*)&S[(mt*16 + lm)*SP + ks*32 + koct*8];
            acc[mt] = __builtin_amdgcn_mfma_f32_16x16x32_bf16(sf, ff, acc[mt], 0, 0, 0);
        }
    }
    ushort* AT = FW;
    if (lm < 3) {
#pragma unroll
        for (int mt = 0; mt < 4; ++mt) {
            u16x4 pk;
            pk.x = f2bf(acc[mt][0]);
            pk.y = f2bf(acc[mt][1]);
            pk.z = f2bf(acc[mt][2]);
            pk.w = f2bf(acc[mt][3]);
            *(u16x4*)&AT[lm*SP + mt*16 + koct*4] = pk;
        }
    }
    ushort* Arow = A + (size_t)n * Ktot;
    if (l < 24) {
        int ch = l >> 3, cc = (l & 7) * 8;
        *(uint4*)&Arow[ch*64 + cc] = *(const uint4*)&AT[ch*SP + cc];
    }
}

// dense_1 = fluid_vel @ W_d1 + b_d1 -> out1 columns [64..96)
__global__ void dense1_kernel(const float* __restrict__ vel,
                              const float* __restrict__ Wd,
                              const float* __restrict__ bd,
                              float* __restrict__ out1, int M) {
    int t = blockIdx.x * blockDim.x + threadIdx.x;
    if (t >= M*32) return;
    int n = t >> 5, c = t & 31;
    float v = bd[c] + vel[n*3+0]*Wd[c] + vel[n*3+1]*Wd[32+c] + vel[n*3+2]*Wd[64+c];
    out1[(size_t)n*96 + 64 + c] = v;
}

// ---- merged weight prep: all 5 transposes in one launch.
__device__ __forceinline__ void wprep_one(const float* Wc, int Kc,
                                          const float* Wd, int N,
                                          ushort* Wt, int Ktot, int t) {
    int nn = t / Ktot, k = t - nn * Ktot;
    float v;
    if (k < Kc) {
        int cinl = Kc >> 6;
        int ch = k >> 6, cl = k & 63;
        v = Wc[(size_t)(cl*cinl + ch)*N + nn];
    } else {
        v = Wd[(size_t)(k-Kc)*N + nn];
    }
    Wt[(size_t)nn*Ktot + k] = f2bf(v);
}

__global__ void wprep_all_kernel(
        const float* __restrict__ W_wall1, const float* __restrict__ W_fluid1,
        const float* __restrict__ W_c2, const float* __restrict__ W_d2,
        const float* __restrict__ W_c3, const float* __restrict__ W_d3,
        const float* __restrict__ W_c4,
        ushort* __restrict__ Wt1a, ushort* __restrict__ Wt1b,
        ushort* __restrict__ Wt2, ushort* __restrict__ Wt3,
        ushort* __restrict__ Wt4) {
    int t = blockIdx.x * 256 + threadIdx.x;
    const int s0 = 32*192, s1 = s0 + 32*192, s2 = s1 + 64*6240,
              s3 = s2 + 64*4160, s4 = s3 + 192*64;
    if (t < s0) {
        wprep_one(W_wall1, 192, nullptr, 32, Wt1a, 192, t);
    } else if (t < s1) {
        wprep_one(W_fluid1, 192, nullptr, 32, Wt1b, 192, t - s0);
    } else if (t < s2) {
        wprep_one(W_c2, 6144, W_d2, 64, Wt2, 6240, t - s1);
    } else if (t < s3) {
        wprep_one(W_c3, 4096, W_d3, 64, Wt3, 4160, t - s2);
    } else if (t < s4) {
        int u = t - s3;
        int row = u >> 6, ch = u & 63;       // row = cell*3 + c
        int cell = row / 3, c = row - cell*3;
        Wt4[row*64 + ch] = f2bf(W_c4[(cell*64 + ch)*3 + c]);
    }
}

// ---- L1 GEMM, fused epilogue, both halves (blockIdx.y: 0=wall, 1=fluid).
__global__ __launch_bounds__(256) void gemm_l1_kernel(
        const ushort* __restrict__ A0, const ushort* __restrict__ A1,
        const ushort* __restrict__ Wt0, const ushort* __restrict__ Wt1,
        const float* __restrict__ b0, const float* __restrict__ b1,
        float* __restrict__ out1, int M) {
    constexpr int Ktot = 192, nks = 6, NCT = 2;
    const ushort* A;  const ushort* Wt; const float* bias; int ocol;
    if (blockIdx.y == 0) { A = A0; Wt = Wt0; bias = b0; ocol = 0; }
    else                 { A = A1; Wt = Wt1; bias = b1; ocol = 32; }
    int tid = threadIdx.x;
    int w = tid >> 6, l = tid & 63;
    int lm = l & 15, koct = l >> 4;
    int mb = blockIdx.x;

    const ushort* Arow = A + (size_t)(mb*64 + w*16 + lm) * Ktot + koct*8;
    const ushort* Wrow = Wt + (size_t)lm * Ktot + koct*8;

    f32x4 acc[NCT];
#pragma unroll
    for (int ct = 0; ct < NCT; ++ct) acc[ct] = (f32x4){0.f,0.f,0.f,0.f};

    bf16x8 ac = *(const bf16x8*)(Arow);
    bf16x8 bc[NCT];
#pragma unroll
    for (int ct = 0; ct < NCT; ++ct)
        bc[ct] = *(const bf16x8*)(Wrow + (size_t)ct*16*Ktot);
#pragma unroll
    for (int ks = 0; ks < nks; ++ks) {
        bf16x8 an = {};
        bf16x8 bn[NCT] = {};
        if (ks + 1 < nks) {
            int k0 = (ks + 1) * 32;
            an = *(const bf16x8*)(Arow + k0);
#pragma unroll
            for (int ct = 0; ct < NCT; ++ct)
                bn[ct] = *(const bf16x8*)(Wrow + (size_t)ct*16*Ktot + k0);
        }
#pragma unroll
        for (int ct = 0; ct < NCT; ++ct)
            acc[ct] = __builtin_amdgcn_mfma_f32_16x16x32_bf16(ac, bc[ct], acc[ct], 0, 0, 0);
        ac = an;
#pragma unroll
        for (int ct = 0; ct < NCT; ++ct) bc[ct] = bn[ct];
    }

    int rbase = mb*64 + w*16 + koct*4;
#pragma unroll
    for (int ct = 0; ct < NCT; ++ct) {
        int col = ct*16 + lm;
        float bb = bias[col];
#pragma unroll
        for (int r = 0; r < 4; ++r) {
            float v = fmaxf(acc[ct][r] + bb, 0.f);
            out1[(size_t)(rbase + r)*96 + ocol + col] = v;
        }
    }
}

// Sum KS partial slabs + bias (+b2) (+res) (+relu) -> out[m_base+row][ocol..]
// Optionally also writes a bf16 shadow copy (outb, stride 64, N must be 64).
__global__ __launch_bounds__(256) void reduce_kernel(
        const float* __restrict__ Cpart, int rows, int N, int KS,
        const float* __restrict__ b1, const float* __restrict__ b2,
        const float* __restrict__ res,
        float* __restrict__ out, int ostride, int ocol, int m_base, int relu,
        ushort* __restrict__ outb) {
    int idx = blockIdx.x * 256 + threadIdx.x;
    int nq = N >> 2;
    if (idx >= rows * nq) return;
    int row = idx / nq;
    int c4 = (idx - row * nq) * 4;
    size_t slab = (size_t)rows * N;
    const float* p = Cpart + (size_t)row * N + c4;
    float s0 = 0.f, s1 = 0.f, s2 = 0.f, s3 = 0.f;
    for (int k = 0; k < KS; ++k) {
        float4 v = *(const float4*)(p + slab * k);
        s0 += v.x; s1 += v.y; s2 += v.z; s3 += v.w;
    }
    s0 += b1[c4+0]; s1 += b1[c4+1]; s2 += b1[c4+2]; s3 += b1[c4+3];
    if (b2) { s0 += b2[c4+0]; s1 += b2[c4+1]; s2 += b2[c4+2]; s3 += b2[c4+3]; }
    if (res) {
        const float* rr = res + (size_t)(m_base + row) * 64 + c4;
        s0 += rr[0]; s1 += rr[1]; s2 += rr[2]; s3 += rr[3];
    }
    if (relu) {
        s0 = fmaxf(s0, 0.f); s1 = fmaxf(s1, 0.f);
        s2 = fmaxf(s2, 0.f); s3 = fmaxf(s3, 0.f);
    }
    float* o = out + (size_t)(m_base + row) * ostride + ocol + c4;
    *(float4*)o = make_float4(s0, s1, s2, s3);
    if (outb) {
        u16x4 pk;
        pk.x = f2bf(s0); pk.y = f2bf(s1); pk.z = f2bf(s2); pk.w = f2bf(s3);
        *(u16x4*)&outb[(size_t)(m_base + row) * 64 + c4] = pk;
    }
}

// ---- Layer 4: G[16000,192] = out3b @ Wt4^T via bf16 MFMA.
__global__ __launch_bounds__(256) void g4_mfma_kernel(
        const ushort* __restrict__ out3b,   // [M][64] bf16
        const ushort* __restrict__ Wt4,     // [192][64] bf16
        float* __restrict__ G, int M) {
    constexpr int SP = 72;
    __shared__ ushort Bsh[192*SP];
    int tid = threadIdx.x;
    for (int u = tid; u < 192*8; u += 256) {       // 192 rows x 8x16B units
        int row = u >> 3, seg = u & 7;
        *(bf16x8*)&Bsh[row*SP + seg*8] = *(const bf16x8*)&Wt4[row*64 + seg*8];
    }
    __syncthreads();
    int w = tid >> 6, l = tid & 63;
    int lm = l & 15, koct = l >> 4;
    int row0 = blockIdx.x*64 + w*16;               // M=16000=250*64: in range
    const ushort* Arow = out3b + (size_t)(row0 + lm)*64 + koct*8;
    bf16x8 a0 = *(const bf16x8*)(Arow);
    bf16x8 a1 = *(const bf16x8*)(Arow + 32);
    f32x4 acc[12];
#pragma unroll
    for (int nt = 0; nt < 12; ++nt) acc[nt] = (f32x4){0.f,0.f,0.f,0.f};
#pragma unroll
    for (int nt = 0; nt < 12; ++nt) {
        bf16x8 b = *(const bf16x8*)&Bsh[(nt*16 + lm)*SP + koct*8];
        acc[nt] = __builtin_amdgcn_mfma_f32_16x16x32_bf16(a0, b, acc[nt], 0, 0, 0);
    }
#pragma unroll
    for (int nt = 0; nt < 12; ++nt) {
        bf16x8 b = *(const bf16x8*)&Bsh[(nt*16 + lm)*SP + 32 + koct*8];
        acc[nt] = __builtin_amdgcn_mfma_f32_16x16x32_bf16(a1, b, acc[nt], 0, 0, 0);
    }
#pragma unroll
    for (int nt = 0; nt < 12; ++nt)
#pragma unroll
        for (int r = 0; r < 4; ++r)
            G[(size_t)(row0 + koct*4 + r)*192 + nt*16 + lm] = acc[nt][r];
}

// out[n][c] = biases + dense + sum_k win * sum_{8 cells} tri_w * G[j_k][cell][c]
__global__ __launch_bounds__(256) void l4_scatter_kernel(
        const float* __restrict__ G,
        const float4* __restrict__ geomF,
        const int*   __restrict__ geomI,
        const int*   __restrict__ nbr,
        const float* __restrict__ out3,
        const float* __restrict__ Wd4,
        const float* __restrict__ b_c4, const float* __restrict__ b_d4,
        float* __restrict__ out, int M) {
    __shared__ float Wsh[192];
    int tid = threadIdx.x;
    if (tid < 192) Wsh[tid] = Wd4[tid];
    __syncthreads();
    int wv = tid >> 6, l = tid & 63;
    int n = blockIdx.x*4 + wv;
    if (n >= M) return;
    size_t t = (size_t)n * KNBR + l;
    float4 g = geomF[t];
    int cell = geomI[t];
    int j = nbr[t];
    float a0 = 0.f, a1 = 0.f, a2 = 0.f;
    float win = g.x;
    if (win > 0.f) {
        float x1 = g.y, y1 = g.z, z1 = g.w;
        float x0 = 1.f-x1, y0 = 1.f-y1, z0 = 1.f-z1;
        float w[8] = {x0*y0*z0, x0*y0*z1, x0*y1*z0, x0*y1*z1,
                      x1*y0*z0, x1*y0*z1, x1*y1*z0, x1*y1*z1};
        const int co[8] = {0,1,4,5,16,17,20,21};
        const float* Gj = G + (size_t)j*192;
#pragma unroll
        for (int i = 0; i < 8; ++i) {
            const float* Gc = Gj + (cell + co[i])*3;
            float ww = win * w[i];
            a0 += ww*Gc[0]; a1 += ww*Gc[1]; a2 += ww*Gc[2];
        }
    }
    {   // dense tail
        float v = out3[(size_t)n*64 + l];
        a0 += v*Wsh[l*3+0]; a1 += v*Wsh[l*3+1]; a2 += v*Wsh[l*3+2];
    }
#pragma unroll
    for (int off = 32; off; off >>= 1) {
        a0 += __shfl_down(a0, off, 64);
        a1 += __shfl_down(a1, off, 64);
        a2 += __shfl_down(a2, off, 64);
    }
    if (l == 0) {
        out[n*3+0] = a0 + b_c4[0] + b_d4[0];
        out[n*3+1] = a1 + b_c4[1] + b_d4[1];
        out[n*3+2] = a2 + b_c4[2] + b_d4[2];
    }
}

extern "C" void kernel_launch(void* const* d_in, const int* in_sizes, int n_in,
                              void* d_out, int out_size, void* d_ws, size_t ws_size,
                              hipStream_t stream) {
    const float* fluid_pos = (const float*)d_in[0];
    const float* wall_pos  = (const float*)d_in[1];
    const float* fluid_vel = (const float*)d_in[2];
    const float* wall_nrm  = (const float*)d_in[3];
    const int*   nbr_wf    = (const int*)d_in[4];
    const int*   nbr_ff    = (const int*)d_in[6];
    const float* W_wall1   = (const float*)d_in[8];
    const float* b_wall1   = (const float*)d_in[9];
    const float* W_fluid1  = (const float*)d_in[10];
    const float* b_fluid1  = (const float*)d_in[11];
    const float* W_d1      = (const float*)d_in[12];
    const float* b_d1      = (const float*)d_in[13];
    const float* W_c2      = (const float*)d_in[14];
    const float* b_c2      = (const float*)d_in[15];
    const float* W_d2      = (const float*)d_in[16];
    const float* b_d2      = (const float*)d_in[17];
    const float* W_c3      = (const float*)d_in[18];
    const float* b_c3      = (const float*)d_in[19];
    const float* W_d3      = (const float*)d_in[20];
    const float* b_d3      = (const float*)d_in[21];
    const float* W_c4      = (const float*)d_in[22];
    const float* b_c4      = (const float*)d_in[23];
    const float* W_d4      = (const float*)d_in[24];
    const float* b_d4      = (const float*)d_in[25];

    const int M = M_FLUID;
    char* ws = (char*)d_ws;
    size_t off = 0;
    auto carve = [&](size_t bytes) {
        char* p = ws + off;
        off = (off + bytes + 255) & ~(size_t)255;
        return p;
    };
    float4* gF_ff = (float4*)carve((size_t)M*KNBR*sizeof(float4));
    int*    gI_ff = (int*)   carve((size_t)M*KNBR*4);
    float4* gF_wf = (float4*)carve((size_t)M*KNBR*sizeof(float4));
    int*    gI_wf = (int*)   carve((size_t)M*KNBR*4);
    float*  out1  = (float*) carve((size_t)M*96*4);
    float*  out2  = (float*) carve((size_t)M*64*4);
    float*  out3  = (float*) carve((size_t)M*64*4);
    ushort* out3b = (ushort*)carve((size_t)M*64*2);
    float*  Gbuf  = (float*) carve((size_t)M*192*4);
    ushort* Wt1a  = (ushort*)carve((size_t)32*192*2);
    ushort* Wt1b  = (ushort*)carve((size_t)32*192*2);
    ushort* Wt2   = (ushort*)carve((size_t)64*6240*2);
    ushort* Wt3   = (ushort*)carve((size_t)64*4160*2);
    ushort* Wt4   = (ushort*)carve((size_t)192*64*2);
    float*  Cpart = (float*) carve((size_t)8*M*64*4);   // KS=8 full-M slabs
    ushort* Abuf  = (ushort*)(ws + off);                // ping-pong chunks

    // ---- merged weight prep (1 dispatch; perm matches abuild k'=ch*64+cell)
    {
        int total = 2*32*192 + 64*6240 + 64*4160 + 192*64;
        wprep_all_kernel<<<(total + 255)/256, 256, 0, stream>>>(
            W_wall1, W_fluid1, W_c2, W_d2, W_c3, W_d3, W_c4,
            Wt1a, Wt1b, Wt2, Wt3, Wt4);
    }
    // ---- geometry, both neighbor lists (1 dispatch)
    {
        int total = M * KNBR, thr = 256;
        geom_dual_kernel<<<dim3((total + thr - 1)/thr, 2), thr, 0, stream>>>(
            fluid_pos, wall_pos, nbr_ff, nbr_wf, gF_ff, gI_ff, gF_wf, gI_wf, M);
    }
    dense1_kernel<<<(M*32 + 255)/256, 256, 0, stream>>>(fluid_vel, W_d1, b_d1, out1, M);

    // ---- layer 1 (both convs): abuild (1 dispatch) + fused gemm (1 dispatch)
    {
        ushort* A0 = Abuf;
        ushort* A1 = Abuf + (size_t)M*192;
        abuild_s3_dual_kernel<<<dim3(M, 2), 64, 0, stream>>>(
            wall_nrm, fluid_vel, nbr_wf, nbr_ff,
            gF_wf, gI_wf, gF_ff, gI_ff, A0, A1, M);
        gemm_l1_kernel<<<dim3(M/64, 2), 256, 0, stream>>>(
            A0, A1, Wt1a, Wt1b, b_wall1, b_fluid1, out1, M);
    }
    // ---- layer 2 (cin=96): pipelined fused abuild||gemm, 4 chunks of 4000
    {
        const int Ktot = 6240, nks = 195, KS = 8, R = 4000, NCH = 4;
        ushort* Ab[2] = {Abuf, Abuf + (size_t)R*Ktot};
        size_t dyn = (size_t)4*(64+48)*72*2;       // 64512 B
        int mt = (R + 127)/128;                    // 32
        for (int c = 0; c <= NCH; ++c) {
            int G_g = (c > 0)   ? mt*KS : 0;       // 256
            int G_a = (c < NCH) ? R/4   : 0;       // 1000
            int gm0 = (c-1)*R, am0 = c*R;
            fused_stage_kernel<96><<<G_g + G_a, 256, dyn, stream>>>(
                Ab[(c-1) & 1], Ktot, Wt2, Cpart, R, gm0, nks, KS, M, G_g,
                out1, nbr_ff, gF_ff, gI_ff, out1, Ab[c & 1], am0, am0 + R);
        }
        reduce_kernel<<<(M*16 + 255)/256, 256, 0, stream>>>(
            Cpart, M, 64, KS, b_c2, b_d2, nullptr, out2, 64, 0, 0, 1, nullptr);
    }
    // ---- layer 3 (cin=64, residual): same pipeline
    {
        const int Ktot = 4160, nks = 130, KS = 8, R = 4000, NCH = 4;
        ushort* Ab[2] = {Abuf, Abuf + (size_t)R*Ktot};
        size_t dyn = (size_t)4*(64+32)*72*2;       // 55296 B
        int mt = (R + 127)/128;
        for (int c = 0; c <= NCH; ++c) {
            int G_g = (c > 0)   ? mt*KS : 0;
            int G_a = (c < NCH) ? R/4   : 0;
            int gm0 = (c-1)*R, am0 = c*R;
            fused_stage_kernel<64><<<G_g + G_a, 256, dyn, stream>>>(
                Ab[(c-1) & 1], Ktot, Wt3, Cpart, R, gm0, nks, KS, M, G_g,
                out2, nbr_ff, gF_ff, gI_ff, out2, Ab[c & 1], am0, am0 + R);
        }
        reduce_kernel<<<(M*16 + 255)/256, 256, 0, stream>>>(
            Cpart, M, 64, KS, b_c3, b_d3, out2, out3, 64, 0, 0, 1, out3b);
    }
    // ---- layer 4 (cout=3): G via MFMA + per-pair gather
    g4_mfma_kernel<<<M/64, 256, 0, stream>>>(out3b, Wt4, Gbuf, M);
    l4_scatter_kernel<<<(M+3)/4, 256, 0, stream>>>(
        Gbuf, gF_ff, gI_ff, nbr_ff, out3, W_d4, b_c4, b_d4, (float*)d_out, M);
}

// Round 12
// 369.417 us; speedup vs baseline: 1.1733x; 1.1733x over previous
//
#include <hip/hip_runtime.h>
#include <hip/hip_bf16.h>

// ---------------------------------------------------------------------------
// Net_19378892440061: ContinuousConv fluid network, Round 12.
// Changes vs Round 11: REVERT to round-10 structure (R11 fused pipeline
// regressed: uniform dynamic-LDS gave gemm blocks abuild's 64.5 KB footprint,
// halving occupancy; pipeline head/tail bubbles ate the overlap).
// On top of round 10:
//  - bf16 feature shadows: abuild gathers bf16 (out1b/out2b) instead of fp32
//    (bit-identical values, half the gather traffic). out1 fp32 is dead ->
//    removed entirely (gemm_l1 + dense1 write bf16 directly); out2 keeps
//    fp32 (residual) + bf16 shadow via reduce_kernel's outb path.
// ---------------------------------------------------------------------------

#define M_FLUID 16000
#define KNBR 64

typedef __attribute__((ext_vector_type(8))) short bf16x8;
typedef __attribute__((ext_vector_type(4))) float f32x4;
typedef __attribute__((ext_vector_type(4))) unsigned short u16x4;

__device__ __forceinline__ ushort f2bf(float f) {
    __hip_bfloat16 h = __float2bfloat16(f);   // RNE
    return *(ushort*)&h;
}

__device__ __forceinline__ float sgnf(float v) {
    return (v > 0.f) ? 1.f : ((v < 0.f) ? -1.f : 0.f);
}

// Volume-preserving ball->cube map (matches reference _ball_to_cube, fp32).
__device__ __forceinline__ void ball_to_cube(float x, float y, float z,
                                             float& xc, float& yc, float& zc) {
    const float eps = 1e-12f;
    float sq  = x*x + y*y + z*z;
    float nrm = sqrtf(fmaxf(sq, eps));
    float rho = sqrtf(fmaxf(x*x + y*y, eps));
    bool  top = (1.25f*z*z > x*x + y*y);
    float s_top = sqrtf(3.0f*nrm/(nrm + fabsf(z)));
    float xs = top ? x*s_top : x*nrm/rho;
    float ys = top ? y*s_top : y*nrm/rho;
    float zs = top ? sgnf(z)*nrm : 1.5f*z;
    if (sq < eps) { xs = 0.f; ys = 0.f; zs = 0.f; }
    float rxy = sqrtf(fmaxf(xs*xs + ys*ys, eps));
    bool use_x = fabsf(ys) <= fabsf(xs);
    float dx = (use_x && fabsf(xs) > eps) ? xs : 1.0f;
    float dy = (!use_x && fabsf(ys) > eps) ? ys : 1.0f;
    const float c4pi = 1.2732395447351628f;  // 4/pi
    float xc_, yc_;
    if (use_x) {
        xc_ = sgnf(xs)*rxy;
        yc_ = sgnf(xs)*rxy*c4pi*atanf(ys/dx);
    } else {
        xc_ = sgnf(ys)*rxy*c4pi*atanf(xs/dy);
        yc_ = sgnf(ys)*rxy;
    }
    if (xs*xs + ys*ys < eps) { xc_ = 0.f; yc_ = 0.f; }
    xc = xc_; yc = yc_; zc = zs;
}

// Per-pair geometry for BOTH neighbor lists (blockIdx.y: 0=fluid, 1=wall).
__global__ void geom_dual_kernel(const float* __restrict__ fluid_pos,
                                 const float* __restrict__ wall_pos,
                                 const int*  __restrict__ nbrF,
                                 const int*  __restrict__ nbrW,
                                 float4* __restrict__ gFf, int* __restrict__ gIf,
                                 float4* __restrict__ gFw, int* __restrict__ gIw,
                                 int M) {
    int t = blockIdx.x * blockDim.x + threadIdx.x;
    if (t >= M * KNBR) return;
    const float* pos_in; const int* nbr; float4* geomF; int* geomI; int excl_self;
    if (blockIdx.y == 0) { pos_in = fluid_pos; nbr = nbrF; geomF = gFf; geomI = gIf; excl_self = 1; }
    else                 { pos_in = wall_pos;  nbr = nbrW; geomF = gFw; geomI = gIw; excl_self = 0; }
    int n = t >> 6;
    int k = t & 63;
    int j = nbr[t];
    float px = fluid_pos[n*3+0], py = fluid_pos[n*3+1], pz = fluid_pos[n*3+2];
    float qx = pos_in[(size_t)j*3+0], qy = pos_in[(size_t)j*3+1], qz = pos_in[(size_t)j*3+2];
    float dx = qx - px, dy = qy - py, dz = qz - pz;

    bool valid;
    if (k == 0) {
        // reproduce numpy fp32 distance exactly (no FMA contraction)
#pragma clang fp contract(off)
        float d2f = dx*dx + dy*dy;
        d2f = d2f + dz*dz;
        double d2 = (double)d2f;
        const double RADIUS_D = 0.5*(6.0*1.5*0.025);  // 0.1125
        valid = d2 < RADIUS_D*RADIUS_D;
        if (excl_self) valid = valid && (d2 > 1e-18);
    } else {
        valid = (j != 0);  // ascending neighbor ids: 0 past slot 0 == padding
    }

    const float Rf = (float)(0.5*(6.0*1.5*0.025));
    float ux = dx / Rf, uy = dy / Rf, uz = dz / Rf;
    float r2 = ux*ux + uy*uy; r2 += uz*uz;
    float w1 = 1.f - r2;
    float win = fminf(fmaxf(w1*w1*w1, 0.f), 1.f);

    float bx, by, bz;
    ball_to_cube(ux, uy, uz, bx, by, bz);
    float cx = fminf(fmaxf((bx*0.5f + 0.5f)*3.f, 0.f), 3.f);
    float cy = fminf(fmaxf((by*0.5f + 0.5f)*3.f, 0.f), 3.f);
    float cz = fminf(fmaxf((bz*0.5f + 0.5f)*3.f, 0.f), 3.f);
    float ix = fminf(fmaxf(floorf(cx), 0.f), 2.f);
    float iy = fminf(fmaxf(floorf(cy), 0.f), 2.f);
    float iz = fminf(fmaxf(floorf(cz), 0.f), 2.f);
    float fx = cx - ix, fy = cy - iy, fz = cz - iz;
    int cell = ((int)ix*4 + (int)iy)*4 + (int)iz;

    geomF[t] = make_float4(valid ? win : 0.f, fx, fy, fz);
    geomI[t] = cell;
}

// ---- MFMA-scatter abuild for CIN in {64, 96}. One wave = one particle.
// feat/dense are bf16 shadows (bit-identical to f2bf of the fp32 values).
template<int CIN>
__global__ __launch_bounds__(64) void abuild_s_kernel(
        const ushort* __restrict__ feat,
        const int*   __restrict__ nbr,
        const float4* __restrict__ geomF,
        const int*   __restrict__ geomI,
        const ushort* __restrict__ dense,
        ushort* __restrict__ A,
        int m0, int m1, int Ktot) {
    constexpr int SP = 72;              // row stride (elems): 144B, 16B-aligned
    constexpr int NT = CIN / 16;        // 6 (cin96) or 4 (cin64)
    __shared__ ushort S[64*SP];
    __shared__ ushort FW[CIN*SP];
    int l = threadIdx.x;
    int n = m0 + blockIdx.x;
    if (n >= m1) return;

    // 1. zero S
    {
        uint4 z = make_uint4(0,0,0,0);
        uint4* Sv = (uint4*)S;
#pragma unroll
        for (int i = 0; i < (64*SP*2)/(16*64); ++i)   // 9 iters
            Sv[l + 64*i] = z;
    }
    // 2. geometry -> S scatter (lane l owns neighbor k=l; distinct columns)
    size_t t = (size_t)n * KNBR + l;
    float4 g = geomF[t];
    int cell = geomI[t];
    int j = nbr[t];
    {
        float win = g.x;
        float x1 = g.y, y1 = g.z, z1 = g.w;
        float x0 = 1.f-x1, y0 = 1.f-y1, z0 = 1.f-z1;
        float w00 = y0*z0*win, w01 = y0*z1*win, w10 = y1*z0*win, w11 = y1*z1*win;
        ushort* Sc = S + cell*SP + l;
        Sc[0*SP]  = f2bf(x0*w00);
        Sc[1*SP]  = f2bf(x0*w01);
        Sc[4*SP]  = f2bf(x0*w10);
        Sc[5*SP]  = f2bf(x0*w11);
        Sc[16*SP] = f2bf(x1*w00);
        Sc[17*SP] = f2bf(x1*w01);
        Sc[20*SP] = f2bf(x1*w10);
        Sc[21*SP] = f2bf(x1*w11);
    }
    // 3. FW build: lane l streams neighbor j's bf16 feature row -> FW[ch][l]
    {
        const ushort* frow = feat + (size_t)j * CIN;
#pragma unroll
        for (int c8 = 0; c8 < CIN; c8 += 8) {
            bf16x8 v = *(const bf16x8*)(frow + c8);
#pragma unroll
            for (int i = 0; i < 8; ++i)
                FW[(c8+i)*SP + l] = (ushort)v[i];
        }
    }
    // 4. per-particle MFMA: A_t[cell,ch] = sum_k S[cell,k]*FW[ch,k]
    int lm = l & 15, koct = l >> 4;
    f32x4 acc[4][NT];
#pragma unroll
    for (int mt = 0; mt < 4; ++mt)
#pragma unroll
        for (int nt = 0; nt < NT; ++nt)
            acc[mt][nt] = (f32x4){0.f, 0.f, 0.f, 0.f};
#pragma unroll
    for (int ks = 0; ks < 2; ++ks) {
        bf16x8 sf[4];
#pragma unroll
        for (int mt = 0; mt < 4; ++mt)
            sf[mt] = *(const bf16x8*)&S[(mt*16 + lm)*SP + ks*32 + koct*8];
#pragma unroll
        for (int nt = 0; nt < NT; ++nt) {
            bf16x8 ff = *(const bf16x8*)&FW[(nt*16 + lm)*SP + ks*32 + koct*8];
#pragma unroll
            for (int mt = 0; mt < 4; ++mt)
                acc[mt][nt] = __builtin_amdgcn_mfma_f32_16x16x32_bf16(
                                  sf[mt], ff, acc[mt][nt], 0, 0, 0);
        }
    }
    // 5. C/D: col(=ch)=lane&15, row(=cell)=(lane>>4)*4+reg -> AT[ch][cell]
    ushort* AT = FW;
#pragma unroll
    for (int nt = 0; nt < NT; ++nt)
#pragma unroll
        for (int mt = 0; mt < 4; ++mt) {
            u16x4 pk;
            pk.x = f2bf(acc[mt][nt][0]);
            pk.y = f2bf(acc[mt][nt][1]);
            pk.z = f2bf(acc[mt][nt][2]);
            pk.w = f2bf(acc[mt][nt][3]);
            *(u16x4*)&AT[(nt*16 + lm)*SP + mt*16 + koct*4] = pk;
        }
    // 6. coalesced writeback, k' = ch*64 + cell
    ushort* Arow = A + (size_t)(n - m0) * Ktot;
#pragma unroll
    for (int it = 0; it < CIN/8; ++it) {
        int i = l + 64*it;
        int ch = i >> 3, cc = (i & 7) * 8;
        uint4 v = *(const uint4*)&AT[ch*SP + cc];
        *(uint4*)&Arow[(ch << 6) + cc] = v;
    }
    // 7. dense tail (bf16 shadow: direct copy)
#pragma unroll
    for (int c0 = 0; c0 < CIN; c0 += 64) {
        int ch = c0 + l;
        if (ch < CIN) Arow[64*CIN + ch] = dense[(size_t)n*CIN + ch];
    }
}

// ---- MFMA-scatter abuild for CIN=3, BOTH L1 convs in one launch.
__global__ __launch_bounds__(64) void abuild_s3_dual_kernel(
        const float* __restrict__ featW, const float* __restrict__ featF,
        const int*   __restrict__ nbrW,  const int*   __restrict__ nbrF,
        const float4* __restrict__ gFw,  const int* __restrict__ gIw,
        const float4* __restrict__ gFf,  const int* __restrict__ gIf,
        ushort* __restrict__ A0, ushort* __restrict__ A1, int M) {
    constexpr int SP = 72;
    constexpr int Ktot = 192;
    __shared__ ushort S[64*SP];
    __shared__ ushort FW[16*SP];
    const float* feat; const int* nbr; const float4* geomF; const int* geomI; ushort* A;
    if (blockIdx.y == 0) { feat = featW; nbr = nbrW; geomF = gFw; geomI = gIw; A = A0; }
    else                 { feat = featF; nbr = nbrF; geomF = gFf; geomI = gIf; A = A1; }
    int l = threadIdx.x;
    int n = blockIdx.x;
    if (n >= M) return;

    {   // zero S (9 iters) + FW (144 uint4 units)
        uint4 z = make_uint4(0,0,0,0);
        uint4* Sv = (uint4*)S;
#pragma unroll
        for (int i = 0; i < 9; ++i) Sv[l + 64*i] = z;
        uint4* Fv = (uint4*)FW;
#pragma unroll
        for (int i = 0; i < 3; ++i) {
            int idx = l + 64*i;
            if (idx < (16*SP*2)/16) Fv[idx] = z;
        }
    }
    size_t t = (size_t)n * KNBR + l;
    float4 g = geomF[t];
    int cell = geomI[t];
    int j = nbr[t];
    {
        float win = g.x;
        float x1 = g.y, y1 = g.z, z1 = g.w;
        float x0 = 1.f-x1, y0 = 1.f-y1, z0 = 1.f-z1;
        float w00 = y0*z0*win, w01 = y0*z1*win, w10 = y1*z0*win, w11 = y1*z1*win;
        ushort* Sc = S + cell*SP + l;
        Sc[0*SP]  = f2bf(x0*w00);
        Sc[1*SP]  = f2bf(x0*w01);
        Sc[4*SP]  = f2bf(x0*w10);
        Sc[5*SP]  = f2bf(x0*w11);
        Sc[16*SP] = f2bf(x1*w00);
        Sc[17*SP] = f2bf(x1*w01);
        Sc[20*SP] = f2bf(x1*w10);
        Sc[21*SP] = f2bf(x1*w11);
    }
    {   // FW rows 0..2 = neighbor features
        const float* fr = feat + (size_t)j * 3;
        FW[0*SP + l] = f2bf(fr[0]);
        FW[1*SP + l] = f2bf(fr[1]);
        FW[2*SP + l] = f2bf(fr[2]);
    }
    int lm = l & 15, koct = l >> 4;
    f32x4 acc[4];
#pragma unroll
    for (int mt = 0; mt < 4; ++mt) acc[mt] = (f32x4){0.f,0.f,0.f,0.f};
#pragma unroll
    for (int ks = 0; ks < 2; ++ks) {
        bf16x8 ff = *(const bf16x8*)&FW[lm*SP + ks*32 + koct*8];
#pragma unroll
        for (int mt = 0; mt < 4; ++mt) {
            bf16x8 sf = *(const bf16x8*)&S[(mt*16 + lm)*SP + ks*32 + koct*8];
            acc[mt] = __builtin_amdgcn_mfma_f32_16x16x32_bf16(sf, ff, acc[mt], 0, 0, 0);
        }
    }
    ushort* AT = FW;
    if (lm < 3) {
#pragma unroll
        for (int mt = 0; mt < 4; ++mt) {
            u16x4 pk;
            pk.x = f2bf(acc[mt][0]);
            pk.y = f2bf(acc[mt][1]);
            pk.z = f2bf(acc[mt][2]);
            pk.w = f2bf(acc[mt][3]);
            *(u16x4*)&AT[lm*SP + mt*16 + koct*4] = pk;
        }
    }
    ushort* Arow = A + (size_t)n * Ktot;
    if (l < 24) {
        int ch = l >> 3, cc = (l & 7) * 8;
        *(uint4*)&Arow[ch*64 + cc] = *(const uint4*)&AT[ch*SP + cc];
    }
}

// dense_1 = fluid_vel @ W_d1 + b_d1 -> out1b columns [64..96) (bf16)
__global__ void dense1_kernel(const float* __restrict__ vel,
                              const float* __restrict__ Wd,
                              const float* __restrict__ bd,
                              ushort* __restrict__ out1b, int M) {
    int t = blockIdx.x * blockDim.x + threadIdx.x;
    if (t >= M*32) return;
    int n = t >> 5, c = t & 31;
    float v = bd[c] + vel[n*3+0]*Wd[c] + vel[n*3+1]*Wd[32+c] + vel[n*3+2]*Wd[64+c];
    out1b[(size_t)n*96 + 64 + c] = f2bf(v);
}

// ---- merged weight prep: all 5 transposes in one launch.
__device__ __forceinline__ void wprep_one(const float* Wc, int Kc,
                                          const float* Wd, int N,
                                          ushort* Wt, int Ktot, int t) {
    int nn = t / Ktot, k = t - nn * Ktot;
    float v;
    if (k < Kc) {
        int cinl = Kc >> 6;
        int ch = k >> 6, cl = k & 63;
        v = Wc[(size_t)(cl*cinl + ch)*N + nn];
    } else {
        v = Wd[(size_t)(k-Kc)*N + nn];
    }
    Wt[(size_t)nn*Ktot + k] = f2bf(v);
}

__global__ void wprep_all_kernel(
        const float* __restrict__ W_wall1, const float* __restrict__ W_fluid1,
        const float* __restrict__ W_c2, const float* __restrict__ W_d2,
        const float* __restrict__ W_c3, const float* __restrict__ W_d3,
        const float* __restrict__ W_c4,
        ushort* __restrict__ Wt1a, ushort* __restrict__ Wt1b,
        ushort* __restrict__ Wt2, ushort* __restrict__ Wt3,
        ushort* __restrict__ Wt4) {
    int t = blockIdx.x * 256 + threadIdx.x;
    const int s0 = 32*192, s1 = s0 + 32*192, s2 = s1 + 64*6240,
              s3 = s2 + 64*4160, s4 = s3 + 192*64;
    if (t < s0) {
        wprep_one(W_wall1, 192, nullptr, 32, Wt1a, 192, t);
    } else if (t < s1) {
        wprep_one(W_fluid1, 192, nullptr, 32, Wt1b, 192, t - s0);
    } else if (t < s2) {
        wprep_one(W_c2, 6144, W_d2, 64, Wt2, 6240, t - s1);
    } else if (t < s3) {
        wprep_one(W_c3, 4096, W_d3, 64, Wt3, 4160, t - s2);
    } else if (t < s4) {
        int u = t - s3;
        int row = u >> 6, ch = u & 63;       // row = cell*3 + c
        int cell = row / 3, c = row - cell*3;
        Wt4[row*64 + ch] = f2bf(W_c4[(cell*64 + ch)*3 + c]);
    }
}

// ---- L1 GEMM, fused epilogue, both halves (blockIdx.y: 0=wall, 1=fluid).
// out1b[:, ocol..ocol+32) = bf16(relu(A @ Wt^T + b)).
__global__ __launch_bounds__(256) void gemm_l1_kernel(
        const ushort* __restrict__ A0, const ushort* __restrict__ A1,
        const ushort* __restrict__ Wt0, const ushort* __restrict__ Wt1,
        const float* __restrict__ b0, const float* __restrict__ b1,
        ushort* __restrict__ out1b, int M) {
    constexpr int Ktot = 192, nks = 6, NCT = 2;
    const ushort* A;  const ushort* Wt; const float* bias; int ocol;
    if (blockIdx.y == 0) { A = A0; Wt = Wt0; bias = b0; ocol = 0; }
    else                 { A = A1; Wt = Wt1; bias = b1; ocol = 32; }
    int tid = threadIdx.x;
    int w = tid >> 6, l = tid & 63;
    int lm = l & 15, koct = l >> 4;
    int mb = blockIdx.x;

    const ushort* Arow = A + (size_t)(mb*64 + w*16 + lm) * Ktot + koct*8;
    const ushort* Wrow = Wt + (size_t)lm * Ktot + koct*8;

    f32x4 acc[NCT];
#pragma unroll
    for (int ct = 0; ct < NCT; ++ct) acc[ct] = (f32x4){0.f,0.f,0.f,0.f};

    bf16x8 ac = *(const bf16x8*)(Arow);
    bf16x8 bc[NCT];
#pragma unroll
    for (int ct = 0; ct < NCT; ++ct)
        bc[ct] = *(const bf16x8*)(Wrow + (size_t)ct*16*Ktot);
#pragma unroll
    for (int ks = 0; ks < nks; ++ks) {
        bf16x8 an = {};
        bf16x8 bn[NCT] = {};
        if (ks + 1 < nks) {
            int k0 = (ks + 1) * 32;
            an = *(const bf16x8*)(Arow + k0);
#pragma unroll
            for (int ct = 0; ct < NCT; ++ct)
                bn[ct] = *(const bf16x8*)(Wrow + (size_t)ct*16*Ktot + k0);
        }
#pragma unroll
        for (int ct = 0; ct < NCT; ++ct)
            acc[ct] = __builtin_amdgcn_mfma_f32_16x16x32_bf16(ac, bc[ct], acc[ct], 0, 0, 0);
        ac = an;
#pragma unroll
        for (int ct = 0; ct < NCT; ++ct) bc[ct] = bn[ct];
    }

    int rbase = mb*64 + w*16 + koct*4;
#pragma unroll
    for (int ct = 0; ct < NCT; ++ct) {
        int col = ct*16 + lm;
        float bb = bias[col];
#pragma unroll
        for (int r = 0; r < 4; ++r) {
            float v = fmaxf(acc[ct][r] + bb, 0.f);
            out1b[(size_t)(rbase + r)*96 + ocol + col] = f2bf(v);
        }
    }
}

// GEMM v7 (layers 2/3, N=64): LDS-staged A+B, double-buffered, BK=32.
__global__ __launch_bounds__(256) void gemm7_kernel(
        const ushort* __restrict__ A, int Ktot,
        const ushort* __restrict__ Wt,
        float* __restrict__ Cpart, int rows, int nks, int KS) {
    constexpr int N = 64;
    constexpr int SP = 40;
    __shared__ ushort Ash[2][128][SP];
    __shared__ ushort Bsh[2][64][SP];
    int tid = threadIdx.x;
    int w = tid >> 6, l = tid & 63;
    int lm = l & 15, koct = l >> 4;
    int mb = blockIdx.x;
    int per = (nks + KS - 1) / KS;
    int ksa = blockIdx.y * per;
    int ksb = ksa + per; if (ksb > nks) ksb = nks;
    int nk = ksb - ksa;

    f32x4 acc[2][4];
#pragma unroll
    for (int fi = 0; fi < 2; ++fi)
#pragma unroll
        for (int nt = 0; nt < 4; ++nt) acc[fi][nt] = (f32x4){0.f,0.f,0.f,0.f};

    int rS  = tid >> 2;          // 0..63
    int kb4 = tid & 3;           // 16B unit within 64B row-chunk
    int rA0 = mb*128 + rS;       if (rA0 >= rows) rA0 = rows - 1;
    int rA1 = mb*128 + rS + 64;  if (rA1 >= rows) rA1 = rows - 1;

    bf16x8 ra0, ra1, rb;
    auto load_regs = [&](int ks) {
        int kk = ks*32 + kb4*8;
        ra0 = *(const bf16x8*)&A[(size_t)rA0*Ktot + kk];
        ra1 = *(const bf16x8*)&A[(size_t)rA1*Ktot + kk];
        rb  = *(const bf16x8*)&Wt[(size_t)rS*Ktot + kk];
    };
    auto store_lds = [&](int buf) {
        *(bf16x8*)&Ash[buf][rS][kb4*8]      = ra0;
        *(bf16x8*)&Ash[buf][rS + 64][kb4*8] = ra1;
        *(bf16x8*)&Bsh[buf][rS][kb4*8]      = rb;
    };

    if (nk > 0) {
        load_regs(ksa);
        store_lds(0);
        __syncthreads();
        for (int i = 0; i < nk; ++i) {
            int buf = i & 1;
            bool nxt = (i + 1 < nk);
            if (nxt) load_regs(ksa + i + 1);
            bf16x8 a0 = *(const bf16x8*)&Ash[buf][w*32 + lm][koct*8];
            bf16x8 a1 = *(const bf16x8*)&Ash[buf][w*32 + 16 + lm][koct*8];
#pragma unroll
            for (int nt = 0; nt < 4; ++nt) {
                bf16x8 b = *(const bf16x8*)&Bsh[buf][nt*16 + lm][koct*8];
                acc[0][nt] = __builtin_amdgcn_mfma_f32_16x16x32_bf16(a0, b, acc[0][nt], 0, 0, 0);
                acc[1][nt] = __builtin_amdgcn_mfma_f32_16x16x32_bf16(a1, b, acc[1][nt], 0, 0, 0);
            }
            if (nxt) {
                store_lds(buf ^ 1);
                __syncthreads();
            }
        }
    }

    float* Cp = Cpart + ((size_t)blockIdx.y * rows + mb*128 + w*32) * N;
    int gr0 = mb*128 + w*32;
#pragma unroll
    for (int fi = 0; fi < 2; ++fi)
#pragma unroll
        for (int nt = 0; nt < 4; ++nt)
#pragma unroll
            for (int r = 0; r < 4; ++r) {
                int row = fi*16 + koct*4 + r;
                if (gr0 + row < rows)
                    Cp[row * N + nt*16 + lm] = acc[fi][nt][r];
            }
}

// Sum KS partial slabs + bias (+b2) (+res) (+relu) -> out[m_base+row][ocol..]
// Optionally also writes a bf16 shadow copy (outb, stride 64, N must be 64).
__global__ __launch_bounds__(256) void reduce_kernel(
        const float* __restrict__ Cpart, int rows, int N, int KS,
        const float* __restrict__ b1, const float* __restrict__ b2,
        const float* __restrict__ res,
        float* __restrict__ out, int ostride, int ocol, int m_base, int relu,
        ushort* __restrict__ outb) {
    int idx = blockIdx.x * 256 + threadIdx.x;
    int nq = N >> 2;
    if (idx >= rows * nq) return;
    int row = idx / nq;
    int c4 = (idx - row * nq) * 4;
    size_t slab = (size_t)rows * N;
    const float* p = Cpart + (size_t)row * N + c4;
    float s0 = 0.f, s1 = 0.f, s2 = 0.f, s3 = 0.f;
    for (int k = 0; k < KS; ++k) {
        float4 v = *(const float4*)(p + slab * k);
        s0 += v.x; s1 += v.y; s2 += v.z; s3 += v.w;
    }
    s0 += b1[c4+0]; s1 += b1[c4+1]; s2 += b1[c4+2]; s3 += b1[c4+3];
    if (b2) { s0 += b2[c4+0]; s1 += b2[c4+1]; s2 += b2[c4+2]; s3 += b2[c4+3]; }
    if (res) {
        const float* rr = res + (size_t)(m_base + row) * 64 + c4;
        s0 += rr[0]; s1 += rr[1]; s2 += rr[2]; s3 += rr[3];
    }
    if (relu) {
        s0 = fmaxf(s0, 0.f); s1 = fmaxf(s1, 0.f);
        s2 = fmaxf(s2, 0.f); s3 = fmaxf(s3, 0.f);
    }
    if (out) {
        float* o = out + (size_t)(m_base + row) * ostride + ocol + c4;
        *(float4*)o = make_float4(s0, s1, s2, s3);
    }
    if (outb) {
        u16x4 pk;
        pk.x = f2bf(s0); pk.y = f2bf(s1); pk.z = f2bf(s2); pk.w = f2bf(s3);
        *(u16x4*)&outb[(size_t)(m_base + row) * 64 + c4] = pk;
    }
}

// ---- Layer 4: G[16000,192] = out3b @ Wt4^T via bf16 MFMA.
__global__ __launch_bounds__(256) void g4_mfma_kernel(
        const ushort* __restrict__ out3b,   // [M][64] bf16
        const ushort* __restrict__ Wt4,     // [192][64] bf16
        float* __restrict__ G, int M) {
    constexpr int SP = 72;
    __shared__ ushort Bsh[192*SP];
    int tid = threadIdx.x;
    for (int u = tid; u < 192*8; u += 256) {       // 192 rows x 8x16B units
        int row = u >> 3, seg = u & 7;
        *(bf16x8*)&Bsh[row*SP + seg*8] = *(const bf16x8*)&Wt4[row*64 + seg*8];
    }
    __syncthreads();
    int w = tid >> 6, l = tid & 63;
    int lm = l & 15, koct = l >> 4;
    int row0 = blockIdx.x*64 + w*16;               // M=16000=250*64: in range
    const ushort* Arow = out3b + (size_t)(row0 + lm)*64 + koct*8;
    bf16x8 a0 = *(const bf16x8*)(Arow);
    bf16x8 a1 = *(const bf16x8*)(Arow + 32);
    f32x4 acc[12];
#pragma unroll
    for (int nt = 0; nt < 12; ++nt) acc[nt] = (f32x4){0.f,0.f,0.f,0.f};
#pragma unroll
    for (int nt = 0; nt < 12; ++nt) {
        bf16x8 b = *(const bf16x8*)&Bsh[(nt*16 + lm)*SP + koct*8];
        acc[nt] = __builtin_amdgcn_mfma_f32_16x16x32_bf16(a0, b, acc[nt], 0, 0, 0);
    }
#pragma unroll
    for (int nt = 0; nt < 12; ++nt) {
        bf16x8 b = *(const bf16x8*)&Bsh[(nt*16 + lm)*SP + 32 + koct*8];
        acc[nt] = __builtin_amdgcn_mfma_f32_16x16x32_bf16(a1, b, acc[nt], 0, 0, 0);
    }
#pragma unroll
    for (int nt = 0; nt < 12; ++nt)
#pragma unroll
        for (int r = 0; r < 4; ++r)
            G[(size_t)(row0 + koct*4 + r)*192 + nt*16 + lm] = acc[nt][r];
}

// out[n][c] = biases + dense + sum_k win * sum_{8 cells} tri_w * G[j_k][cell][c]
__global__ __launch_bounds__(256) void l4_scatter_kernel(
        const float* __restrict__ G,
        const float4* __restrict__ geomF,
        const int*   __restrict__ geomI,
        const int*   __restrict__ nbr,
        const float* __restrict__ out3,
        const float* __restrict__ Wd4,
        const float* __restrict__ b_c4, const float* __restrict__ b_d4,
        float* __restrict__ out, int M) {
    __shared__ float Wsh[192];
    int tid = threadIdx.x;
    if (tid < 192) Wsh[tid] = Wd4[tid];
    __syncthreads();
    int wv = tid >> 6, l = tid & 63;
    int n = blockIdx.x*4 + wv;
    if (n >= M) return;
    size_t t = (size_t)n * KNBR + l;
    float4 g = geomF[t];
    int cell = geomI[t];
    int j = nbr[t];
    float a0 = 0.f, a1 = 0.f, a2 = 0.f;
    float win = g.x;
    if (win > 0.f) {
        float x1 = g.y, y1 = g.z, z1 = g.w;
        float x0 = 1.f-x1, y0 = 1.f-y1, z0 = 1.f-z1;
        float w[8] = {x0*y0*z0, x0*y0*z1, x0*y1*z0, x0*y1*z1,
                      x1*y0*z0, x1*y0*z1, x1*y1*z0, x1*y1*z1};
        const int co[8] = {0,1,4,5,16,17,20,21};
        const float* Gj = G + (size_t)j*192;
#pragma unroll
        for (int i = 0; i < 8; ++i) {
            const float* Gc = Gj + (cell + co[i])*3;
            float ww = win * w[i];
            a0 += ww*Gc[0]; a1 += ww*Gc[1]; a2 += ww*Gc[2];
        }
    }
    {   // dense tail
        float v = out3[(size_t)n*64 + l];
        a0 += v*Wsh[l*3+0]; a1 += v*Wsh[l*3+1]; a2 += v*Wsh[l*3+2];
    }
#pragma unroll
    for (int off = 32; off; off >>= 1) {
        a0 += __shfl_down(a0, off, 64);
        a1 += __shfl_down(a1, off, 64);
        a2 += __shfl_down(a2, off, 64);
    }
    if (l == 0) {
        out[n*3+0] = a0 + b_c4[0] + b_d4[0];
        out[n*3+1] = a1 + b_c4[1] + b_d4[1];
        out[n*3+2] = a2 + b_c4[2] + b_d4[2];
    }
}

extern "C" void kernel_launch(void* const* d_in, const int* in_sizes, int n_in,
                              void* d_out, int out_size, void* d_ws, size_t ws_size,
                              hipStream_t stream) {
    const float* fluid_pos = (const float*)d_in[0];
    const float* wall_pos  = (const float*)d_in[1];
    const float* fluid_vel = (const float*)d_in[2];
    const float* wall_nrm  = (const float*)d_in[3];
    const int*   nbr_wf    = (const int*)d_in[4];
    const int*   nbr_ff    = (const int*)d_in[6];
    const float* W_wall1   = (const float*)d_in[8];
    const float* b_wall1   = (const float*)d_in[9];
    const float* W_fluid1  = (const float*)d_in[10];
    const float* b_fluid1  = (const float*)d_in[11];
    const float* W_d1      = (const float*)d_in[12];
    const float* b_d1      = (const float*)d_in[13];
    const float* W_c2      = (const float*)d_in[14];
    const float* b_c2      = (const float*)d_in[15];
    const float* W_d2      = (const float*)d_in[16];
    const float* b_d2      = (const float*)d_in[17];
    const float* W_c3      = (const float*)d_in[18];
    const float* b_c3      = (const float*)d_in[19];
    const float* W_d3      = (const float*)d_in[20];
    const float* b_d3      = (const float*)d_in[21];
    const float* W_c4      = (const float*)d_in[22];
    const float* b_c4      = (const float*)d_in[23];
    const float* W_d4      = (const float*)d_in[24];
    const float* b_d4      = (const float*)d_in[25];

    const int M = M_FLUID;
    char* ws = (char*)d_ws;
    size_t off = 0;
    auto carve = [&](size_t bytes) {
        char* p = ws + off;
        off = (off + bytes + 255) & ~(size_t)255;
        return p;
    };
    float4* gF_ff = (float4*)carve((size_t)M*KNBR*sizeof(float4));
    int*    gI_ff = (int*)   carve((size_t)M*KNBR*4);
    float4* gF_wf = (float4*)carve((size_t)M*KNBR*sizeof(float4));
    int*    gI_wf = (int*)   carve((size_t)M*KNBR*4);
    ushort* out1b = (ushort*)carve((size_t)M*96*2);
    float*  out2  = (float*) carve((size_t)M*64*4);
    ushort* out2b = (ushort*)carve((size_t)M*64*2);
    float*  out3  = (float*) carve((size_t)M*64*4);
    ushort* out3b = (ushort*)carve((size_t)M*64*2);
    float*  Gbuf  = (float*) carve((size_t)M*192*4);
    ushort* Wt1a  = (ushort*)carve((size_t)32*192*2);
    ushort* Wt1b  = (ushort*)carve((size_t)32*192*2);
    ushort* Wt2   = (ushort*)carve((size_t)64*6240*2);
    ushort* Wt3   = (ushort*)carve((size_t)64*4160*2);
    ushort* Wt4   = (ushort*)carve((size_t)192*64*2);
    float*  Cpart = (float*) carve((size_t)8*M*64*4);   // KS=8 slabs
    ushort* Abuf  = (ushort*)(ws + off);
    size_t availA = (ws_size > off) ? (ws_size - off) : 0;

    auto chunkR = [&](int Ktot) -> int {
        size_t r = availA / ((size_t)Ktot * 2);   // bf16 A
        if (r > (size_t)M) r = (size_t)M;
        r &= ~(size_t)127;
        if (r < 128) r = 128;
        return (int)r;
    };

    // ---- merged weight prep (1 dispatch; perm matches abuild k'=ch*64+cell)
    {
        int total = 2*32*192 + 64*6240 + 64*4160 + 192*64;
        wprep_all_kernel<<<(total + 255)/256, 256, 0, stream>>>(
            W_wall1, W_fluid1, W_c2, W_d2, W_c3, W_d3, W_c4,
            Wt1a, Wt1b, Wt2, Wt3, Wt4);
    }
    // ---- geometry, both neighbor lists (1 dispatch)
    {
        int total = M * KNBR, thr = 256;
        geom_dual_kernel<<<dim3((total + thr - 1)/thr, 2), thr, 0, stream>>>(
            fluid_pos, wall_pos, nbr_ff, nbr_wf, gF_ff, gI_ff, gF_wf, gI_wf, M);
    }
    dense1_kernel<<<(M*32 + 255)/256, 256, 0, stream>>>(fluid_vel, W_d1, b_d1, out1b, M);

    // ---- layer 1 (both convs): abuild (1 dispatch) + fused gemm (1 dispatch)
    {
        ushort* A0 = Abuf;
        ushort* A1 = Abuf + (size_t)M*192;
        abuild_s3_dual_kernel<<<dim3(M, 2), 64, 0, stream>>>(
            wall_nrm, fluid_vel, nbr_wf, nbr_ff,
            gF_wf, gI_wf, gF_ff, gI_ff, A0, A1, M);
        gemm_l1_kernel<<<dim3(M/64, 2), 256, 0, stream>>>(
            A0, A1, Wt1a, Wt1b, b_wall1, b_fluid1, out1b, M);
    }
    // ---- layer 2: cin=96 -> out2 (fp32) + out2b (bf16 shadow)
    {
        int Ktot = 6240, nks = 195, KS = 8, R = chunkR(Ktot);
        for (int m0 = 0; m0 < M; m0 += R) {
            int rows = (M - m0 < R) ? (M - m0) : R;
            abuild_s_kernel<96><<<rows, 64, 0, stream>>>(
                out1b, nbr_ff, gF_ff, gI_ff, out1b, Abuf, m0, m0+rows, Ktot);
            gemm7_kernel<<<dim3((rows+127)/128, KS), 256, 0, stream>>>(
                Abuf, Ktot, Wt2, Cpart, rows, nks, KS);
            reduce_kernel<<<(rows*16 + 255)/256, 256, 0, stream>>>(
                Cpart, rows, 64, KS, b_c2, b_d2, nullptr,
                out2, 64, 0, m0, 1, out2b);
        }
    }
    // ---- layer 3: cin=64, residual -> out3 (+bf16 shadow for g4)
    {
        int Ktot = 4160, nks = 130, KS = 8, R = chunkR(Ktot);
        for (int m0 = 0; m0 < M; m0 += R) {
            int rows = (M - m0 < R) ? (M - m0) : R;
            abuild_s_kernel<64><<<rows, 64, 0, stream>>>(
                out2b, nbr_ff, gF_ff, gI_ff, out2b, Abuf, m0, m0+rows, Ktot);
            gemm7_kernel<<<dim3((rows+127)/128, KS), 256, 0, stream>>>(
                Abuf, Ktot, Wt3, Cpart, rows, nks, KS);
            reduce_kernel<<<(rows*16 + 255)/256, 256, 0, stream>>>(
                Cpart, rows, 64, KS, b_c3, b_d3, out2,
                out3, 64, 0, m0, 1, out3b);
        }
    }
    // ---- layer 4 (cout=3): G via MFMA + per-pair gather
    g4_mfma_kernel<<<M/64, 256, 0, stream>>>(out3b, Wt4, Gbuf, M);
    l4_scatter_kernel<<<(M+3)/4, 256, 0, stream>>>(
        Gbuf, gF_ff, gI_ff, nbr_ff, out3, W_d4, b_c4, b_d4, (float*)d_out, M);
}

// Round 13
// 358.025 us; speedup vs baseline: 1.2106x; 1.0318x over previous
//
#include <hip/hip_runtime.h>
#include <hip/hip_bf16.h>

// ---------------------------------------------------------------------------
// Net_19378892440061: ContinuousConv fluid network, Round 13.
// Changes vs Round 12:
//  - geomF compressed fp32x4 -> bf16x4 (8 B/pair): win/tri fractions only
//    feed bf16 S-entries and tri-weights; halves geometry write + 5 reads.
//  - G compressed fp32 -> bf16 (12.3 -> 6.1 MB, L2-resident): halves
//    l4_scatter's scattered reads and g4's writes.
//  - Cpart stays fp32 (partial-sum precision).
// ---------------------------------------------------------------------------

#define M_FLUID 16000
#define KNBR 64

typedef __attribute__((ext_vector_type(8))) short bf16x8;
typedef __attribute__((ext_vector_type(4))) float f32x4;
typedef __attribute__((ext_vector_type(4))) unsigned short u16x4;

__device__ __forceinline__ ushort f2bf(float f) {
    __hip_bfloat16 h = __float2bfloat16(f);   // RNE
    return *(ushort*)&h;
}
__device__ __forceinline__ float bf2f(ushort u) {
    union { uint i; float f; } c; c.i = (uint)u << 16; return c.f;
}

__device__ __forceinline__ float sgnf(float v) {
    return (v > 0.f) ? 1.f : ((v < 0.f) ? -1.f : 0.f);
}

// Volume-preserving ball->cube map (matches reference _ball_to_cube, fp32).
__device__ __forceinline__ void ball_to_cube(float x, float y, float z,
                                             float& xc, float& yc, float& zc) {
    const float eps = 1e-12f;
    float sq  = x*x + y*y + z*z;
    float nrm = sqrtf(fmaxf(sq, eps));
    float rho = sqrtf(fmaxf(x*x + y*y, eps));
    bool  top = (1.25f*z*z > x*x + y*y);
    float s_top = sqrtf(3.0f*nrm/(nrm + fabsf(z)));
    float xs = top ? x*s_top : x*nrm/rho;
    float ys = top ? y*s_top : y*nrm/rho;
    float zs = top ? sgnf(z)*nrm : 1.5f*z;
    if (sq < eps) { xs = 0.f; ys = 0.f; zs = 0.f; }
    float rxy = sqrtf(fmaxf(xs*xs + ys*ys, eps));
    bool use_x = fabsf(ys) <= fabsf(xs);
    float dx = (use_x && fabsf(xs) > eps) ? xs : 1.0f;
    float dy = (!use_x && fabsf(ys) > eps) ? ys : 1.0f;
    const float c4pi = 1.2732395447351628f;  // 4/pi
    float xc_, yc_;
    if (use_x) {
        xc_ = sgnf(xs)*rxy;
        yc_ = sgnf(xs)*rxy*c4pi*atanf(ys/dx);
    } else {
        xc_ = sgnf(ys)*rxy*c4pi*atanf(xs/dy);
        yc_ = sgnf(ys)*rxy;
    }
    if (xs*xs + ys*ys < eps) { xc_ = 0.f; yc_ = 0.f; }
    xc = xc_; yc = yc_; zc = zs;
}

// Per-pair geometry for BOTH neighbor lists (blockIdx.y: 0=fluid, 1=wall).
// Output: packed bf16x4 {win, fx, fy, fz} + cell index.
__global__ void geom_dual_kernel(const float* __restrict__ fluid_pos,
                                 const float* __restrict__ wall_pos,
                                 const int*  __restrict__ nbrF,
                                 const int*  __restrict__ nbrW,
                                 ushort4* __restrict__ gFf, int* __restrict__ gIf,
                                 ushort4* __restrict__ gFw, int* __restrict__ gIw,
                                 int M) {
    int t = blockIdx.x * blockDim.x + threadIdx.x;
    if (t >= M * KNBR) return;
    const float* pos_in; const int* nbr; ushort4* geomF; int* geomI; int excl_self;
    if (blockIdx.y == 0) { pos_in = fluid_pos; nbr = nbrF; geomF = gFf; geomI = gIf; excl_self = 1; }
    else                 { pos_in = wall_pos;  nbr = nbrW; geomF = gFw; geomI = gIw; excl_self = 0; }
    int n = t >> 6;
    int k = t & 63;
    int j = nbr[t];
    float px = fluid_pos[n*3+0], py = fluid_pos[n*3+1], pz = fluid_pos[n*3+2];
    float qx = pos_in[(size_t)j*3+0], qy = pos_in[(size_t)j*3+1], qz = pos_in[(size_t)j*3+2];
    float dx = qx - px, dy = qy - py, dz = qz - pz;

    bool valid;
    if (k == 0) {
        // reproduce numpy fp32 distance exactly (no FMA contraction)
#pragma clang fp contract(off)
        float d2f = dx*dx + dy*dy;
        d2f = d2f + dz*dz;
        double d2 = (double)d2f;
        const double RADIUS_D = 0.5*(6.0*1.5*0.025);  // 0.1125
        valid = d2 < RADIUS_D*RADIUS_D;
        if (excl_self) valid = valid && (d2 > 1e-18);
    } else {
        valid = (j != 0);  // ascending neighbor ids: 0 past slot 0 == padding
    }

    const float Rf = (float)(0.5*(6.0*1.5*0.025));
    float ux = dx / Rf, uy = dy / Rf, uz = dz / Rf;
    float r2 = ux*ux + uy*uy; r2 += uz*uz;
    float w1 = 1.f - r2;
    float win = fminf(fmaxf(w1*w1*w1, 0.f), 1.f);

    float bx, by, bz;
    ball_to_cube(ux, uy, uz, bx, by, bz);
    float cx = fminf(fmaxf((bx*0.5f + 0.5f)*3.f, 0.f), 3.f);
    float cy = fminf(fmaxf((by*0.5f + 0.5f)*3.f, 0.f), 3.f);
    float cz = fminf(fmaxf((bz*0.5f + 0.5f)*3.f, 0.f), 3.f);
    float ix = fminf(fmaxf(floorf(cx), 0.f), 2.f);
    float iy = fminf(fmaxf(floorf(cy), 0.f), 2.f);
    float iz = fminf(fmaxf(floorf(cz), 0.f), 2.f);
    float fx = cx - ix, fy = cy - iy, fz = cz - iz;
    int cell = ((int)ix*4 + (int)iy)*4 + (int)iz;

    ushort4 gp;
    gp.x = f2bf(valid ? win : 0.f);
    gp.y = f2bf(fx); gp.z = f2bf(fy); gp.w = f2bf(fz);
    geomF[t] = gp;
    geomI[t] = cell;
}

// ---- MFMA-scatter abuild for CIN in {64, 96}. One wave = one particle.
// feat/dense are bf16 shadows; geomF is packed bf16x4.
template<int CIN>
__global__ __launch_bounds__(64) void abuild_s_kernel(
        const ushort* __restrict__ feat,
        const int*   __restrict__ nbr,
        const ushort4* __restrict__ geomF,
        const int*   __restrict__ geomI,
        const ushort* __restrict__ dense,
        ushort* __restrict__ A,
        int m0, int m1, int Ktot) {
    constexpr int SP = 72;              // row stride (elems): 144B, 16B-aligned
    constexpr int NT = CIN / 16;        // 6 (cin96) or 4 (cin64)
    __shared__ ushort S[64*SP];
    __shared__ ushort FW[CIN*SP];
    int l = threadIdx.x;
    int n = m0 + blockIdx.x;
    if (n >= m1) return;

    // 1. zero S
    {
        uint4 z = make_uint4(0,0,0,0);
        uint4* Sv = (uint4*)S;
#pragma unroll
        for (int i = 0; i < (64*SP*2)/(16*64); ++i)   // 9 iters
            Sv[l + 64*i] = z;
    }
    // 2. geometry -> S scatter (lane l owns neighbor k=l; distinct columns)
    size_t t = (size_t)n * KNBR + l;
    ushort4 gp = geomF[t];
    int cell = geomI[t];
    int j = nbr[t];
    {
        float win = bf2f(gp.x);
        float x1 = bf2f(gp.y), y1 = bf2f(gp.z), z1 = bf2f(gp.w);
        float x0 = 1.f-x1, y0 = 1.f-y1, z0 = 1.f-z1;
        float w00 = y0*z0*win, w01 = y0*z1*win, w10 = y1*z0*win, w11 = y1*z1*win;
        ushort* Sc = S + cell*SP + l;
        Sc[0*SP]  = f2bf(x0*w00);
        Sc[1*SP]  = f2bf(x0*w01);
        Sc[4*SP]  = f2bf(x0*w10);
        Sc[5*SP]  = f2bf(x0*w11);
        Sc[16*SP] = f2bf(x1*w00);
        Sc[17*SP] = f2bf(x1*w01);
        Sc[20*SP] = f2bf(x1*w10);
        Sc[21*SP] = f2bf(x1*w11);
    }
    // 3. FW build: lane l streams neighbor j's bf16 feature row -> FW[ch][l]
    {
        const ushort* frow = feat + (size_t)j * CIN;
#pragma unroll
        for (int c8 = 0; c8 < CIN; c8 += 8) {
            bf16x8 v = *(const bf16x8*)(frow + c8);
#pragma unroll
            for (int i = 0; i < 8; ++i)
                FW[(c8+i)*SP + l] = (ushort)v[i];
        }
    }
    // 4. per-particle MFMA: A_t[cell,ch] = sum_k S[cell,k]*FW[ch,k]
    int lm = l & 15, koct = l >> 4;
    f32x4 acc[4][NT];
#pragma unroll
    for (int mt = 0; mt < 4; ++mt)
#pragma unroll
        for (int nt = 0; nt < NT; ++nt)
            acc[mt][nt] = (f32x4){0.f, 0.f, 0.f, 0.f};
#pragma unroll
    for (int ks = 0; ks < 2; ++ks) {
        bf16x8 sf[4];
#pragma unroll
        for (int mt = 0; mt < 4; ++mt)
            sf[mt] = *(const bf16x8*)&S[(mt*16 + lm)*SP + ks*32 + koct*8];
#pragma unroll
        for (int nt = 0; nt < NT; ++nt) {
            bf16x8 ff = *(const bf16x8*)&FW[(nt*16 + lm)*SP + ks*32 + koct*8];
#pragma unroll
            for (int mt = 0; mt < 4; ++mt)
                acc[mt][nt] = __builtin_amdgcn_mfma_f32_16x16x32_bf16(
                                  sf[mt], ff, acc[mt][nt], 0, 0, 0);
        }
    }
    // 5. C/D: col(=ch)=lane&15, row(=cell)=(lane>>4)*4+reg -> AT[ch][cell]
    ushort* AT = FW;
#pragma unroll
    for (int nt = 0; nt < NT; ++nt)
#pragma unroll
        for (int mt = 0; mt < 4; ++mt) {
            u16x4 pk;
            pk.x = f2bf(acc[mt][nt][0]);
            pk.y = f2bf(acc[mt][nt][1]);
            pk.z = f2bf(acc[mt][nt][2]);
            pk.w = f2bf(acc[mt][nt][3]);
            *(u16x4*)&AT[(nt*16 + lm)*SP + mt*16 + koct*4] = pk;
        }
    // 6. coalesced writeback, k' = ch*64 + cell
    ushort* Arow = A + (size_t)(n - m0) * Ktot;
#pragma unroll
    for (int it = 0; it < CIN/8; ++it) {
        int i = l + 64*it;
        int ch = i >> 3, cc = (i & 7) * 8;
        uint4 v = *(const uint4*)&AT[ch*SP + cc];
        *(uint4*)&Arow[(ch << 6) + cc] = v;
    }
    // 7. dense tail (bf16 shadow: direct copy)
#pragma unroll
    for (int c0 = 0; c0 < CIN; c0 += 64) {
        int ch = c0 + l;
        if (ch < CIN) Arow[64*CIN + ch] = dense[(size_t)n*CIN + ch];
    }
}

// ---- MFMA-scatter abuild for CIN=3, BOTH L1 convs in one launch.
__global__ __launch_bounds__(64) void abuild_s3_dual_kernel(
        const float* __restrict__ featW, const float* __restrict__ featF,
        const int*   __restrict__ nbrW,  const int*   __restrict__ nbrF,
        const ushort4* __restrict__ gFw, const int* __restrict__ gIw,
        const ushort4* __restrict__ gFf, const int* __restrict__ gIf,
        ushort* __restrict__ A0, ushort* __restrict__ A1, int M) {
    constexpr int SP = 72;
    constexpr int Ktot = 192;
    __shared__ ushort S[64*SP];
    __shared__ ushort FW[16*SP];
    const float* feat; const int* nbr; const ushort4* geomF; const int* geomI; ushort* A;
    if (blockIdx.y == 0) { feat = featW; nbr = nbrW; geomF = gFw; geomI = gIw; A = A0; }
    else                 { feat = featF; nbr = nbrF; geomF = gFf; geomI = gIf; A = A1; }
    int l = threadIdx.x;
    int n = blockIdx.x;
    if (n >= M) return;

    {   // zero S (9 iters) + FW (144 uint4 units)
        uint4 z = make_uint4(0,0,0,0);
        uint4* Sv = (uint4*)S;
#pragma unroll
        for (int i = 0; i < 9; ++i) Sv[l + 64*i] = z;
        uint4* Fv = (uint4*)FW;
#pragma unroll
        for (int i = 0; i < 3; ++i) {
            int idx = l + 64*i;
            if (idx < (16*SP*2)/16) Fv[idx] = z;
        }
    }
    size_t t = (size_t)n * KNBR + l;
    ushort4 gp = geomF[t];
    int cell = geomI[t];
    int j = nbr[t];
    {
        float win = bf2f(gp.x);
        float x1 = bf2f(gp.y), y1 = bf2f(gp.z), z1 = bf2f(gp.w);
        float x0 = 1.f-x1, y0 = 1.f-y1, z0 = 1.f-z1;
        float w00 = y0*z0*win, w01 = y0*z1*win, w10 = y1*z0*win, w11 = y1*z1*win;
        ushort* Sc = S + cell*SP + l;
        Sc[0*SP]  = f2bf(x0*w00);
        Sc[1*SP]  = f2bf(x0*w01);
        Sc[4*SP]  = f2bf(x0*w10);
        Sc[5*SP]  = f2bf(x0*w11);
        Sc[16*SP] = f2bf(x1*w00);
        Sc[17*SP] = f2bf(x1*w01);
        Sc[20*SP] = f2bf(x1*w10);
        Sc[21*SP] = f2bf(x1*w11);
    }
    {   // FW rows 0..2 = neighbor features
        const float* fr = feat + (size_t)j * 3;
        FW[0*SP + l] = f2bf(fr[0]);
        FW[1*SP + l] = f2bf(fr[1]);
        FW[2*SP + l] = f2bf(fr[2]);
    }
    int lm = l & 15, koct = l >> 4;
    f32x4 acc[4];
#pragma unroll
    for (int mt = 0; mt < 4; ++mt) acc[mt] = (f32x4){0.f,0.f,0.f,0.f};
#pragma unroll
    for (int ks = 0; ks < 2; ++ks) {
        bf16x8 ff = *(const bf16x8*)&FW[lm*SP + ks*32 + koct*8];
#pragma unroll
        for (int mt = 0; mt < 4; ++mt) {
            bf16x8 sf = *(const bf16x8*)&S[(mt*16 + lm)*SP + ks*32 + koct*8];
            acc[mt] = __builtin_amdgcn_mfma_f32_16x16x32_bf16(sf, ff, acc[mt], 0, 0, 0);
        }
    }
    ushort* AT = FW;
    if (lm < 3) {
#pragma unroll
        for (int mt = 0; mt < 4; ++mt) {
            u16x4 pk;
            pk.x = f2bf(acc[mt][0]);
            pk.y = f2bf(acc[mt][1]);
            pk.z = f2bf(acc[mt][2]);
            pk.w = f2bf(acc[mt][3]);
            *(u16x4*)&AT[lm*SP + mt*16 + koct*4] = pk;
        }
    }
    ushort* Arow = A + (size_t)n * Ktot;
    if (l < 24) {
        int ch = l >> 3, cc = (l & 7) * 8;
        *(uint4*)&Arow[ch*64 + cc] = *(const uint4*)&AT[ch*SP + cc];
    }
}

// dense_1 = fluid_vel @ W_d1 + b_d1 -> out1b columns [64..96) (bf16)
__global__ void dense1_kernel(const float* __restrict__ vel,
                              const float* __restrict__ Wd,
                              const float* __restrict__ bd,
                              ushort* __restrict__ out1b, int M) {
    int t = blockIdx.x * blockDim.x + threadIdx.x;
    if (t >= M*32) return;
    int n = t >> 5, c = t & 31;
    float v = bd[c] + vel[n*3+0]*Wd[c] + vel[n*3+1]*Wd[32+c] + vel[n*3+2]*Wd[64+c];
    out1b[(size_t)n*96 + 64 + c] = f2bf(v);
}

// ---- merged weight prep: all 5 transposes in one launch.
__device__ __forceinline__ void wprep_one(const float* Wc, int Kc,
                                          const float* Wd, int N,
                                          ushort* Wt, int Ktot, int t) {
    int nn = t / Ktot, k = t - nn * Ktot;
    float v;
    if (k < Kc) {
        int cinl = Kc >> 6;
        int ch = k >> 6, cl = k & 63;
        v = Wc[(size_t)(cl*cinl + ch)*N + nn];
    } else {
        v = Wd[(size_t)(k-Kc)*N + nn];
    }
    Wt[(size_t)nn*Ktot + k] = f2bf(v);
}

__global__ void wprep_all_kernel(
        const float* __restrict__ W_wall1, const float* __restrict__ W_fluid1,
        const float* __restrict__ W_c2, const float* __restrict__ W_d2,
        const float* __restrict__ W_c3, const float* __restrict__ W_d3,
        const float* __restrict__ W_c4,
        ushort* __restrict__ Wt1a, ushort* __restrict__ Wt1b,
        ushort* __restrict__ Wt2, ushort* __restrict__ Wt3,
        ushort* __restrict__ Wt4) {
    int t = blockIdx.x * 256 + threadIdx.x;
    const int s0 = 32*192, s1 = s0 + 32*192, s2 = s1 + 64*6240,
              s3 = s2 + 64*4160, s4 = s3 + 192*64;
    if (t < s0) {
        wprep_one(W_wall1, 192, nullptr, 32, Wt1a, 192, t);
    } else if (t < s1) {
        wprep_one(W_fluid1, 192, nullptr, 32, Wt1b, 192, t - s0);
    } else if (t < s2) {
        wprep_one(W_c2, 6144, W_d2, 64, Wt2, 6240, t - s1);
    } else if (t < s3) {
        wprep_one(W_c3, 4096, W_d3, 64, Wt3, 4160, t - s2);
    } else if (t < s4) {
        int u = t - s3;
        int row = u >> 6, ch = u & 63;       // row = cell*3 + c
        int cell = row / 3, c = row - cell*3;
        Wt4[row*64 + ch] = f2bf(W_c4[(cell*64 + ch)*3 + c]);
    }
}

// ---- L1 GEMM, fused epilogue, both halves (blockIdx.y: 0=wall, 1=fluid).
__global__ __launch_bounds__(256) void gemm_l1_kernel(
        const ushort* __restrict__ A0, const ushort* __restrict__ A1,
        const ushort* __restrict__ Wt0, const ushort* __restrict__ Wt1,
        const float* __restrict__ b0, const float* __restrict__ b1,
        ushort* __restrict__ out1b, int M) {
    constexpr int Ktot = 192, nks = 6, NCT = 2;
    const ushort* A;  const ushort* Wt; const float* bias; int ocol;
    if (blockIdx.y == 0) { A = A0; Wt = Wt0; bias = b0; ocol = 0; }
    else                 { A = A1; Wt = Wt1; bias = b1; ocol = 32; }
    int tid = threadIdx.x;
    int w = tid >> 6, l = tid & 63;
    int lm = l & 15, koct = l >> 4;
    int mb = blockIdx.x;

    const ushort* Arow = A + (size_t)(mb*64 + w*16 + lm) * Ktot + koct*8;
    const ushort* Wrow = Wt + (size_t)lm * Ktot + koct*8;

    f32x4 acc[NCT];
#pragma unroll
    for (int ct = 0; ct < NCT; ++ct) acc[ct] = (f32x4){0.f,0.f,0.f,0.f};

    bf16x8 ac = *(const bf16x8*)(Arow);
    bf16x8 bc[NCT];
#pragma unroll
    for (int ct = 0; ct < NCT; ++ct)
        bc[ct] = *(const bf16x8*)(Wrow + (size_t)ct*16*Ktot);
#pragma unroll
    for (int ks = 0; ks < nks; ++ks) {
        bf16x8 an = {};
        bf16x8 bn[NCT] = {};
        if (ks + 1 < nks) {
            int k0 = (ks + 1) * 32;
            an = *(const bf16x8*)(Arow + k0);
#pragma unroll
            for (int ct = 0; ct < NCT; ++ct)
                bn[ct] = *(const bf16x8*)(Wrow + (size_t)ct*16*Ktot + k0);
        }
#pragma unroll
        for (int ct = 0; ct < NCT; ++ct)
            acc[ct] = __builtin_amdgcn_mfma_f32_16x16x32_bf16(ac, bc[ct], acc[ct], 0, 0, 0);
        ac = an;
#pragma unroll
        for (int ct = 0; ct < NCT; ++ct) bc[ct] = bn[ct];
    }

    int rbase = mb*64 + w*16 + koct*4;
#pragma unroll
    for (int ct = 0; ct < NCT; ++ct) {
        int col = ct*16 + lm;
        float bb = bias[col];
#pragma unroll
        for (int r = 0; r < 4; ++r) {
            float v = fmaxf(acc[ct][r] + bb, 0.f);
            out1b[(size_t)(rbase + r)*96 + ocol + col] = f2bf(v);
        }
    }
}

// GEMM v7 (layers 2/3, N=64): LDS-staged A+B, double-buffered, BK=32.
__global__ __launch_bounds__(256) void gemm7_kernel(
        const ushort* __restrict__ A, int Ktot,
        const ushort* __restrict__ Wt,
        float* __restrict__ Cpart, int rows, int nks, int KS) {
    constexpr int N = 64;
    constexpr int SP = 40;
    __shared__ ushort Ash[2][128][SP];
    __shared__ ushort Bsh[2][64][SP];
    int tid = threadIdx.x;
    int w = tid >> 6, l = tid & 63;
    int lm = l & 15, koct = l >> 4;
    int mb = blockIdx.x;
    int per = (nks + KS - 1) / KS;
    int ksa = blockIdx.y * per;
    int ksb = ksa + per; if (ksb > nks) ksb = nks;
    int nk = ksb - ksa;

    f32x4 acc[2][4];
#pragma unroll
    for (int fi = 0; fi < 2; ++fi)
#pragma unroll
        for (int nt = 0; nt < 4; ++nt) acc[fi][nt] = (f32x4){0.f,0.f,0.f,0.f};

    int rS  = tid >> 2;          // 0..63
    int kb4 = tid & 3;           // 16B unit within 64B row-chunk
    int rA0 = mb*128 + rS;       if (rA0 >= rows) rA0 = rows - 1;
    int rA1 = mb*128 + rS + 64;  if (rA1 >= rows) rA1 = rows - 1;

    bf16x8 ra0, ra1, rb;
    auto load_regs = [&](int ks) {
        int kk = ks*32 + kb4*8;
        ra0 = *(const bf16x8*)&A[(size_t)rA0*Ktot + kk];
        ra1 = *(const bf16x8*)&A[(size_t)rA1*Ktot + kk];
        rb  = *(const bf16x8*)&Wt[(size_t)rS*Ktot + kk];
    };
    auto store_lds = [&](int buf) {
        *(bf16x8*)&Ash[buf][rS][kb4*8]      = ra0;
        *(bf16x8*)&Ash[buf][rS + 64][kb4*8] = ra1;
        *(bf16x8*)&Bsh[buf][rS][kb4*8]      = rb;
    };

    if (nk > 0) {
        load_regs(ksa);
        store_lds(0);
        __syncthreads();
        for (int i = 0; i < nk; ++i) {
            int buf = i & 1;
            bool nxt = (i + 1 < nk);
            if (nxt) load_regs(ksa + i + 1);
            bf16x8 a0 = *(const bf16x8*)&Ash[buf][w*32 + lm][koct*8];
            bf16x8 a1 = *(const bf16x8*)&Ash[buf][w*32 + 16 + lm][koct*8];
#pragma unroll
            for (int nt = 0; nt < 4; ++nt) {
                bf16x8 b = *(const bf16x8*)&Bsh[buf][nt*16 + lm][koct*8];
                acc[0][nt] = __builtin_amdgcn_mfma_f32_16x16x32_bf16(a0, b, acc[0][nt], 0, 0, 0);
                acc[1][nt] = __builtin_amdgcn_mfma_f32_16x16x32_bf16(a1, b, acc[1][nt], 0, 0, 0);
            }
            if (nxt) {
                store_lds(buf ^ 1);
                __syncthreads();
            }
        }
    }

    float* Cp = Cpart + ((size_t)blockIdx.y * rows + mb*128 + w*32) * N;
    int gr0 = mb*128 + w*32;
#pragma unroll
    for (int fi = 0; fi < 2; ++fi)
#pragma unroll
        for (int nt = 0; nt < 4; ++nt)
#pragma unroll
            for (int r = 0; r < 4; ++r) {
                int row = fi*16 + koct*4 + r;
                if (gr0 + row < rows)
                    Cp[row * N + nt*16 + lm] = acc[fi][nt][r];
            }
}

// Sum KS partial slabs + bias (+b2) (+res) (+relu) -> out[m_base+row][ocol..]
// Optionally also writes a bf16 shadow copy (outb, stride 64, N must be 64).
__global__ __launch_bounds__(256) void reduce_kernel(
        const float* __restrict__ Cpart, int rows, int N, int KS,
        const float* __restrict__ b1, const float* __restrict__ b2,
        const float* __restrict__ res,
        float* __restrict__ out, int ostride, int ocol, int m_base, int relu,
        ushort* __restrict__ outb) {
    int idx = blockIdx.x * 256 + threadIdx.x;
    int nq = N >> 2;
    if (idx >= rows * nq) return;
    int row = idx / nq;
    int c4 = (idx - row * nq) * 4;
    size_t slab = (size_t)rows * N;
    const float* p = Cpart + (size_t)row * N + c4;
    float s0 = 0.f, s1 = 0.f, s2 = 0.f, s3 = 0.f;
    for (int k = 0; k < KS; ++k) {
        float4 v = *(const float4*)(p + slab * k);
        s0 += v.x; s1 += v.y; s2 += v.z; s3 += v.w;
    }
    s0 += b1[c4+0]; s1 += b1[c4+1]; s2 += b1[c4+2]; s3 += b1[c4+3];
    if (b2) { s0 += b2[c4+0]; s1 += b2[c4+1]; s2 += b2[c4+2]; s3 += b2[c4+3]; }
    if (res) {
        const float* rr = res + (size_t)(m_base + row) * 64 + c4;
        s0 += rr[0]; s1 += rr[1]; s2 += rr[2]; s3 += rr[3];
    }
    if (relu) {
        s0 = fmaxf(s0, 0.f); s1 = fmaxf(s1, 0.f);
        s2 = fmaxf(s2, 0.f); s3 = fmaxf(s3, 0.f);
    }
    if (out) {
        float* o = out + (size_t)(m_base + row) * ostride + ocol + c4;
        *(float4*)o = make_float4(s0, s1, s2, s3);
    }
    if (outb) {
        u16x4 pk;
        pk.x = f2bf(s0); pk.y = f2bf(s1); pk.z = f2bf(s2); pk.w = f2bf(s3);
        *(u16x4*)&outb[(size_t)(m_base + row) * 64 + c4] = pk;
    }
}

// ---- Layer 4: G[16000,192] (bf16) = out3b @ Wt4^T via bf16 MFMA.
__global__ __launch_bounds__(256) void g4_mfma_kernel(
        const ushort* __restrict__ out3b,   // [M][64] bf16
        const ushort* __restrict__ Wt4,     // [192][64] bf16
        ushort* __restrict__ G, int M) {
    constexpr int SP = 72;
    __shared__ ushort Bsh[192*SP];
    int tid = threadIdx.x;
    for (int u = tid; u < 192*8; u += 256) {       // 192 rows x 8x16B units
        int row = u >> 3, seg = u & 7;
        *(bf16x8*)&Bsh[row*SP + seg*8] = *(const bf16x8*)&Wt4[row*64 + seg*8];
    }
    __syncthreads();
    int w = tid >> 6, l = tid & 63;
    int lm = l & 15, koct = l >> 4;
    int row0 = blockIdx.x*64 + w*16;               // M=16000=250*64: in range
    const ushort* Arow = out3b + (size_t)(row0 + lm)*64 + koct*8;
    bf16x8 a0 = *(const bf16x8*)(Arow);
    bf16x8 a1 = *(const bf16x8*)(Arow + 32);
    f32x4 acc[12];
#pragma unroll
    for (int nt = 0; nt < 12; ++nt) acc[nt] = (f32x4){0.f,0.f,0.f,0.f};
#pragma unroll
    for (int nt = 0; nt < 12; ++nt) {
        bf16x8 b = *(const bf16x8*)&Bsh[(nt*16 + lm)*SP + koct*8];
        acc[nt] = __builtin_amdgcn_mfma_f32_16x16x32_bf16(a0, b, acc[nt], 0, 0, 0);
    }
#pragma unroll
    for (int nt = 0; nt < 12; ++nt) {
        bf16x8 b = *(const bf16x8*)&Bsh[(nt*16 + lm)*SP + 32 + koct*8];
        acc[nt] = __builtin_amdgcn_mfma_f32_16x16x32_bf16(a1, b, acc[nt], 0, 0, 0);
    }
#pragma unroll
    for (int nt = 0; nt < 12; ++nt)
#pragma unroll
        for (int r = 0; r < 4; ++r)
            G[(size_t)(row0 + koct*4 + r)*192 + nt*16 + lm] = f2bf(acc[nt][r]);
}

// out[n][c] = biases + dense + sum_k win * sum_{8 cells} tri_w * G[j_k][cell][c]
__global__ __launch_bounds__(256) void l4_scatter_kernel(
        const ushort* __restrict__ G,       // [M][64 cells][3] bf16
        const ushort4* __restrict__ geomF,
        const int*   __restrict__ geomI,
        const int*   __restrict__ nbr,
        const float* __restrict__ out3,
        const float* __restrict__ Wd4,
        const float* __restrict__ b_c4, const float* __restrict__ b_d4,
        float* __restrict__ out, int M) {
    __shared__ float Wsh[192];
    int tid = threadIdx.x;
    if (tid < 192) Wsh[tid] = Wd4[tid];
    __syncthreads();
    int wv = tid >> 6, l = tid & 63;
    int n = blockIdx.x*4 + wv;
    if (n >= M) return;
    size_t t = (size_t)n * KNBR + l;
    ushort4 gp = geomF[t];
    int cell = geomI[t];
    int j = nbr[t];
    float a0 = 0.f, a1 = 0.f, a2 = 0.f;
    float win = bf2f(gp.x);
    if (win > 0.f) {
        float x1 = bf2f(gp.y), y1 = bf2f(gp.z), z1 = bf2f(gp.w);
        float x0 = 1.f-x1, y0 = 1.f-y1, z0 = 1.f-z1;
        float w[8] = {x0*y0*z0, x0*y0*z1, x0*y1*z0, x0*y1*z1,
                      x1*y0*z0, x1*y0*z1, x1*y1*z0, x1*y1*z1};
        const int co[8] = {0,1,4,5,16,17,20,21};
        const ushort* Gj = G + (size_t)j*192;
#pragma unroll
        for (int i = 0; i < 8; ++i) {
            const ushort* Gc = Gj + (cell + co[i])*3;
            float ww = win * w[i];
            a0 += ww*bf2f(Gc[0]); a1 += ww*bf2f(Gc[1]); a2 += ww*bf2f(Gc[2]);
        }
    }
    {   // dense tail
        float v = out3[(size_t)n*64 + l];
        a0 += v*Wsh[l*3+0]; a1 += v*Wsh[l*3+1]; a2 += v*Wsh[l*3+2];
    }
#pragma unroll
    for (int off = 32; off; off >>= 1) {
        a0 += __shfl_down(a0, off, 64);
        a1 += __shfl_down(a1, off, 64);
        a2 += __shfl_down(a2, off, 64);
    }
    if (l == 0) {
        out[n*3+0] = a0 + b_c4[0] + b_d4[0];
        out[n*3+1] = a1 + b_c4[1] + b_d4[1];
        out[n*3+2] = a2 + b_c4[2] + b_d4[2];
    }
}

extern "C" void kernel_launch(void* const* d_in, const int* in_sizes, int n_in,
                              void* d_out, int out_size, void* d_ws, size_t ws_size,
                              hipStream_t stream) {
    const float* fluid_pos = (const float*)d_in[0];
    const float* wall_pos  = (const float*)d_in[1];
    const float* fluid_vel = (const float*)d_in[2];
    const float* wall_nrm  = (const float*)d_in[3];
    const int*   nbr_wf    = (const int*)d_in[4];
    const int*   nbr_ff    = (const int*)d_in[6];
    const float* W_wall1   = (const float*)d_in[8];
    const float* b_wall1   = (const float*)d_in[9];
    const float* W_fluid1  = (const float*)d_in[10];
    const float* b_fluid1  = (const float*)d_in[11];
    const float* W_d1      = (const float*)d_in[12];
    const float* b_d1      = (const float*)d_in[13];
    const float* W_c2      = (const float*)d_in[14];
    const float* b_c2      = (const float*)d_in[15];
    const float* W_d2      = (const float*)d_in[16];
    const float* b_d2      = (const float*)d_in[17];
    const float* W_c3      = (const float*)d_in[18];
    const float* b_c3      = (const float*)d_in[19];
    const float* W_d3      = (const float*)d_in[20];
    const float* b_d3      = (const float*)d_in[21];
    const float* W_c4      = (const float*)d_in[22];
    const float* b_c4      = (const float*)d_in[23];
    const float* W_d4      = (const float*)d_in[24];
    const float* b_d4      = (const float*)d_in[25];

    const int M = M_FLUID;
    char* ws = (char*)d_ws;
    size_t off = 0;
    auto carve = [&](size_t bytes) {
        char* p = ws + off;
        off = (off + bytes + 255) & ~(size_t)255;
        return p;
    };
    ushort4* gF_ff = (ushort4*)carve((size_t)M*KNBR*8);
    int*     gI_ff = (int*)    carve((size_t)M*KNBR*4);
    ushort4* gF_wf = (ushort4*)carve((size_t)M*KNBR*8);
    int*     gI_wf = (int*)    carve((size_t)M*KNBR*4);
    ushort*  out1b = (ushort*) carve((size_t)M*96*2);
    float*   out2  = (float*)  carve((size_t)M*64*4);
    ushort*  out2b = (ushort*) carve((size_t)M*64*2);
    float*   out3  = (float*)  carve((size_t)M*64*4);
    ushort*  out3b = (ushort*) carve((size_t)M*64*2);
    ushort*  Gbuf  = (ushort*) carve((size_t)M*192*2);
    ushort*  Wt1a  = (ushort*) carve((size_t)32*192*2);
    ushort*  Wt1b  = (ushort*) carve((size_t)32*192*2);
    ushort*  Wt2   = (ushort*) carve((size_t)64*6240*2);
    ushort*  Wt3   = (ushort*) carve((size_t)64*4160*2);
    ushort*  Wt4   = (ushort*) carve((size_t)192*64*2);
    float*   Cpart = (float*)  carve((size_t)8*M*64*4);   // KS=8 slabs
    ushort*  Abuf  = (ushort*)(ws + off);
    size_t availA = (ws_size > off) ? (ws_size - off) : 0;

    auto chunkR = [&](int Ktot) -> int {
        size_t r = availA / ((size_t)Ktot * 2);   // bf16 A
        if (r > (size_t)M) r = (size_t)M;
        r &= ~(size_t)127;
        if (r < 128) r = 128;
        return (int)r;
    };

    // ---- merged weight prep (1 dispatch; perm matches abuild k'=ch*64+cell)
    {
        int total = 2*32*192 + 64*6240 + 64*4160 + 192*64;
        wprep_all_kernel<<<(total + 255)/256, 256, 0, stream>>>(
            W_wall1, W_fluid1, W_c2, W_d2, W_c3, W_d3, W_c4,
            Wt1a, Wt1b, Wt2, Wt3, Wt4);
    }
    // ---- geometry, both neighbor lists (1 dispatch)
    {
        int total = M * KNBR, thr = 256;
        geom_dual_kernel<<<dim3((total + thr - 1)/thr, 2), thr, 0, stream>>>(
            fluid_pos, wall_pos, nbr_ff, nbr_wf, gF_ff, gI_ff, gF_wf, gI_wf, M);
    }
    dense1_kernel<<<(M*32 + 255)/256, 256, 0, stream>>>(fluid_vel, W_d1, b_d1, out1b, M);

    // ---- layer 1 (both convs): abuild (1 dispatch) + fused gemm (1 dispatch)
    {
        ushort* A0 = Abuf;
        ushort* A1 = Abuf + (size_t)M*192;
        abuild_s3_dual_kernel<<<dim3(M, 2), 64, 0, stream>>>(
            wall_nrm, fluid_vel, nbr_wf, nbr_ff,
            gF_wf, gI_wf, gF_ff, gI_ff, A0, A1, M);
        gemm_l1_kernel<<<dim3(M/64, 2), 256, 0, stream>>>(
            A0, A1, Wt1a, Wt1b, b_wall1, b_fluid1, out1b, M);
    }
    // ---- layer 2: cin=96 -> out2 (fp32) + out2b (bf16 shadow)
    {
        int Ktot = 6240, nks = 195, KS = 8, R = chunkR(Ktot);
        for (int m0 = 0; m0 < M; m0 += R) {
            int rows = (M - m0 < R) ? (M - m0) : R;
            abuild_s_kernel<96><<<rows, 64, 0, stream>>>(
                out1b, nbr_ff, gF_ff, gI_ff, out1b, Abuf, m0, m0+rows, Ktot);
            gemm7_kernel<<<dim3((rows+127)/128, KS), 256, 0, stream>>>(
                Abuf, Ktot, Wt2, Cpart, rows, nks, KS);
            reduce_kernel<<<(rows*16 + 255)/256, 256, 0, stream>>>(
                Cpart, rows, 64, KS, b_c2, b_d2, nullptr,
                out2, 64, 0, m0, 1, out2b);
        }
    }
    // ---- layer 3: cin=64, residual -> out3 (+bf16 shadow for g4)
    {
        int Ktot = 4160, nks = 130, KS = 8, R = chunkR(Ktot);
        for (int m0 = 0; m0 < M; m0 += R) {
            int rows = (M - m0 < R) ? (M - m0) : R;
            abuild_s_kernel<64><<<rows, 64, 0, stream>>>(
                out2b, nbr_ff, gF_ff, gI_ff, out2b, Abuf, m0, m0+rows, Ktot);
            gemm7_kernel<<<dim3((rows+127)/128, KS), 256, 0, stream>>>(
                Abuf, Ktot, Wt3, Cpart, rows, nks, KS);
            reduce_kernel<<<(rows*16 + 255)/256, 256, 0, stream>>>(
                Cpart, rows, 64, KS, b_c3, b_d3, out2,
                out3, 64, 0, m0, 1, out3b);
        }
    }
    // ---- layer 4 (cout=3): G via MFMA + per-pair gather
    g4_mfma_kernel<<<M/64, 256, 0, stream>>>(out3b, Wt4, Gbuf, M);
    l4_scatter_kernel<<<(M+3)/4, 256, 0, stream>>>(
        Gbuf, gF_ff, gI_ff, nbr_ff, out3, W_d4, b_c4, b_d4, (float*)d_out, M);
}

// Round 14
// 324.973 us; speedup vs baseline: 1.3338x; 1.1017x over previous
//
#include <hip/hip_runtime.h>
#include <hip/hip_bf16.h>

// ---------------------------------------------------------------------------
// Net_19378892440061: ContinuousConv fluid network, Round 14.
// Changes vs Round 13 (byte-trims; pipeline is end-to-end BW-bound):
//  - Cpart fp32 -> bf16 (65 -> 33 MB round trip); re-summed in fp32.
//  - out2/out3 fp32 buffers removed: layer-3 residual reads out2b (bf16),
//    l4_scatter dense tail reads out3b. No remaining fp32 consumers.
// ---------------------------------------------------------------------------

#define M_FLUID 16000
#define KNBR 64

typedef __attribute__((ext_vector_type(8))) short bf16x8;
typedef __attribute__((ext_vector_type(4))) float f32x4;
typedef __attribute__((ext_vector_type(4))) unsigned short u16x4;

__device__ __forceinline__ ushort f2bf(float f) {
    __hip_bfloat16 h = __float2bfloat16(f);   // RNE
    return *(ushort*)&h;
}
__device__ __forceinline__ float bf2f(ushort u) {
    union { uint i; float f; } c; c.i = (uint)u << 16; return c.f;
}

__device__ __forceinline__ float sgnf(float v) {
    return (v > 0.f) ? 1.f : ((v < 0.f) ? -1.f : 0.f);
}

// Volume-preserving ball->cube map (matches reference _ball_to_cube, fp32).
__device__ __forceinline__ void ball_to_cube(float x, float y, float z,
                                             float& xc, float& yc, float& zc) {
    const float eps = 1e-12f;
    float sq  = x*x + y*y + z*z;
    float nrm = sqrtf(fmaxf(sq, eps));
    float rho = sqrtf(fmaxf(x*x + y*y, eps));
    bool  top = (1.25f*z*z > x*x + y*y);
    float s_top = sqrtf(3.0f*nrm/(nrm + fabsf(z)));
    float xs = top ? x*s_top : x*nrm/rho;
    float ys = top ? y*s_top : y*nrm/rho;
    float zs = top ? sgnf(z)*nrm : 1.5f*z;
    if (sq < eps) { xs = 0.f; ys = 0.f; zs = 0.f; }
    float rxy = sqrtf(fmaxf(xs*xs + ys*ys, eps));
    bool use_x = fabsf(ys) <= fabsf(xs);
    float dx = (use_x && fabsf(xs) > eps) ? xs : 1.0f;
    float dy = (!use_x && fabsf(ys) > eps) ? ys : 1.0f;
    const float c4pi = 1.2732395447351628f;  // 4/pi
    float xc_, yc_;
    if (use_x) {
        xc_ = sgnf(xs)*rxy;
        yc_ = sgnf(xs)*rxy*c4pi*atanf(ys/dx);
    } else {
        xc_ = sgnf(ys)*rxy*c4pi*atanf(xs/dy);
        yc_ = sgnf(ys)*rxy;
    }
    if (xs*xs + ys*ys < eps) { xc_ = 0.f; yc_ = 0.f; }
    xc = xc_; yc = yc_; zc = zs;
}

// Per-pair geometry for BOTH neighbor lists (blockIdx.y: 0=fluid, 1=wall).
// Output: packed bf16x4 {win, fx, fy, fz} + cell index.
__global__ void geom_dual_kernel(const float* __restrict__ fluid_pos,
                                 const float* __restrict__ wall_pos,
                                 const int*  __restrict__ nbrF,
                                 const int*  __restrict__ nbrW,
                                 ushort4* __restrict__ gFf, int* __restrict__ gIf,
                                 ushort4* __restrict__ gFw, int* __restrict__ gIw,
                                 int M) {
    int t = blockIdx.x * blockDim.x + threadIdx.x;
    if (t >= M * KNBR) return;
    const float* pos_in; const int* nbr; ushort4* geomF; int* geomI; int excl_self;
    if (blockIdx.y == 0) { pos_in = fluid_pos; nbr = nbrF; geomF = gFf; geomI = gIf; excl_self = 1; }
    else                 { pos_in = wall_pos;  nbr = nbrW; geomF = gFw; geomI = gIw; excl_self = 0; }
    int n = t >> 6;
    int k = t & 63;
    int j = nbr[t];
    float px = fluid_pos[n*3+0], py = fluid_pos[n*3+1], pz = fluid_pos[n*3+2];
    float qx = pos_in[(size_t)j*3+0], qy = pos_in[(size_t)j*3+1], qz = pos_in[(size_t)j*3+2];
    float dx = qx - px, dy = qy - py, dz = qz - pz;

    bool valid;
    if (k == 0) {
        // reproduce numpy fp32 distance exactly (no FMA contraction)
#pragma clang fp contract(off)
        float d2f = dx*dx + dy*dy;
        d2f = d2f + dz*dz;
        double d2 = (double)d2f;
        const double RADIUS_D = 0.5*(6.0*1.5*0.025);  // 0.1125
        valid = d2 < RADIUS_D*RADIUS_D;
        if (excl_self) valid = valid && (d2 > 1e-18);
    } else {
        valid = (j != 0);  // ascending neighbor ids: 0 past slot 0 == padding
    }

    const float Rf = (float)(0.5*(6.0*1.5*0.025));
    float ux = dx / Rf, uy = dy / Rf, uz = dz / Rf;
    float r2 = ux*ux + uy*uy; r2 += uz*uz;
    float w1 = 1.f - r2;
    float win = fminf(fmaxf(w1*w1*w1, 0.f), 1.f);

    float bx, by, bz;
    ball_to_cube(ux, uy, uz, bx, by, bz);
    float cx = fminf(fmaxf((bx*0.5f + 0.5f)*3.f, 0.f), 3.f);
    float cy = fminf(fmaxf((by*0.5f + 0.5f)*3.f, 0.f), 3.f);
    float cz = fminf(fmaxf((bz*0.5f + 0.5f)*3.f, 0.f), 3.f);
    float ix = fminf(fmaxf(floorf(cx), 0.f), 2.f);
    float iy = fminf(fmaxf(floorf(cy), 0.f), 2.f);
    float iz = fminf(fmaxf(floorf(cz), 0.f), 2.f);
    float fx = cx - ix, fy = cy - iy, fz = cz - iz;
    int cell = ((int)ix*4 + (int)iy)*4 + (int)iz;

    ushort4 gp;
    gp.x = f2bf(valid ? win : 0.f);
    gp.y = f2bf(fx); gp.z = f2bf(fy); gp.w = f2bf(fz);
    geomF[t] = gp;
    geomI[t] = cell;
}

// ---- MFMA-scatter abuild for CIN in {64, 96}. One wave = one particle.
template<int CIN>
__global__ __launch_bounds__(64) void abuild_s_kernel(
        const ushort* __restrict__ feat,
        const int*   __restrict__ nbr,
        const ushort4* __restrict__ geomF,
        const int*   __restrict__ geomI,
        const ushort* __restrict__ dense,
        ushort* __restrict__ A,
        int m0, int m1, int Ktot) {
    constexpr int SP = 72;              // row stride (elems): 144B, 16B-aligned
    constexpr int NT = CIN / 16;        // 6 (cin96) or 4 (cin64)
    __shared__ ushort S[64*SP];
    __shared__ ushort FW[CIN*SP];
    int l = threadIdx.x;
    int n = m0 + blockIdx.x;
    if (n >= m1) return;

    // 1. zero S
    {
        uint4 z = make_uint4(0,0,0,0);
        uint4* Sv = (uint4*)S;
#pragma unroll
        for (int i = 0; i < (64*SP*2)/(16*64); ++i)   // 9 iters
            Sv[l + 64*i] = z;
    }
    // 2. geometry -> S scatter (lane l owns neighbor k=l; distinct columns)
    size_t t = (size_t)n * KNBR + l;
    ushort4 gp = geomF[t];
    int cell = geomI[t];
    int j = nbr[t];
    {
        float win = bf2f(gp.x);
        float x1 = bf2f(gp.y), y1 = bf2f(gp.z), z1 = bf2f(gp.w);
        float x0 = 1.f-x1, y0 = 1.f-y1, z0 = 1.f-z1;
        float w00 = y0*z0*win, w01 = y0*z1*win, w10 = y1*z0*win, w11 = y1*z1*win;
        ushort* Sc = S + cell*SP + l;
        Sc[0*SP]  = f2bf(x0*w00);
        Sc[1*SP]  = f2bf(x0*w01);
        Sc[4*SP]  = f2bf(x0*w10);
        Sc[5*SP]  = f2bf(x0*w11);
        Sc[16*SP] = f2bf(x1*w00);
        Sc[17*SP] = f2bf(x1*w01);
        Sc[20*SP] = f2bf(x1*w10);
        Sc[21*SP] = f2bf(x1*w11);
    }
    // 3. FW build: lane l streams neighbor j's bf16 feature row -> FW[ch][l]
    {
        const ushort* frow = feat + (size_t)j * CIN;
#pragma unroll
        for (int c8 = 0; c8 < CIN; c8 += 8) {
            bf16x8 v = *(const bf16x8*)(frow + c8);
#pragma unroll
            for (int i = 0; i < 8; ++i)
                FW[(c8+i)*SP + l] = (ushort)v[i];
        }
    }
    // 4. per-particle MFMA: A_t[cell,ch] = sum_k S[cell,k]*FW[ch,k]
    int lm = l & 15, koct = l >> 4;
    f32x4 acc[4][NT];
#pragma unroll
    for (int mt = 0; mt < 4; ++mt)
#pragma unroll
        for (int nt = 0; nt < NT; ++nt)
            acc[mt][nt] = (f32x4){0.f, 0.f, 0.f, 0.f};
#pragma unroll
    for (int ks = 0; ks < 2; ++ks) {
        bf16x8 sf[4];
#pragma unroll
        for (int mt = 0; mt < 4; ++mt)
            sf[mt] = *(const bf16x8*)&S[(mt*16 + lm)*SP + ks*32 + koct*8];
#pragma unroll
        for (int nt = 0; nt < NT; ++nt) {
            bf16x8 ff = *(const bf16x8*)&FW[(nt*16 + lm)*SP + ks*32 + koct*8];
#pragma unroll
            for (int mt = 0; mt < 4; ++mt)
                acc[mt][nt] = __builtin_amdgcn_mfma_f32_16x16x32_bf16(
                                  sf[mt], ff, acc[mt][nt], 0, 0, 0);
        }
    }
    // 5. C/D: col(=ch)=lane&15, row(=cell)=(lane>>4)*4+reg -> AT[ch][cell]
    ushort* AT = FW;
#pragma unroll
    for (int nt = 0; nt < NT; ++nt)
#pragma unroll
        for (int mt = 0; mt < 4; ++mt) {
            u16x4 pk;
            pk.x = f2bf(acc[mt][nt][0]);
            pk.y = f2bf(acc[mt][nt][1]);
            pk.z = f2bf(acc[mt][nt][2]);
            pk.w = f2bf(acc[mt][nt][3]);
            *(u16x4*)&AT[(nt*16 + lm)*SP + mt*16 + koct*4] = pk;
        }
    // 6. coalesced writeback, k' = ch*64 + cell
    ushort* Arow = A + (size_t)(n - m0) * Ktot;
#pragma unroll
    for (int it = 0; it < CIN/8; ++it) {
        int i = l + 64*it;
        int ch = i >> 3, cc = (i & 7) * 8;
        uint4 v = *(const uint4*)&AT[ch*SP + cc];
        *(uint4*)&Arow[(ch << 6) + cc] = v;
    }
    // 7. dense tail (bf16 shadow: direct copy)
#pragma unroll
    for (int c0 = 0; c0 < CIN; c0 += 64) {
        int ch = c0 + l;
        if (ch < CIN) Arow[64*CIN + ch] = dense[(size_t)n*CIN + ch];
    }
}

// ---- MFMA-scatter abuild for CIN=3, BOTH L1 convs in one launch.
__global__ __launch_bounds__(64) void abuild_s3_dual_kernel(
        const float* __restrict__ featW, const float* __restrict__ featF,
        const int*   __restrict__ nbrW,  const int*   __restrict__ nbrF,
        const ushort4* __restrict__ gFw, const int* __restrict__ gIw,
        const ushort4* __restrict__ gFf, const int* __restrict__ gIf,
        ushort* __restrict__ A0, ushort* __restrict__ A1, int M) {
    constexpr int SP = 72;
    constexpr int Ktot = 192;
    __shared__ ushort S[64*SP];
    __shared__ ushort FW[16*SP];
    const float* feat; const int* nbr; const ushort4* geomF; const int* geomI; ushort* A;
    if (blockIdx.y == 0) { feat = featW; nbr = nbrW; geomF = gFw; geomI = gIw; A = A0; }
    else                 { feat = featF; nbr = nbrF; geomF = gFf; geomI = gIf; A = A1; }
    int l = threadIdx.x;
    int n = blockIdx.x;
    if (n >= M) return;

    {   // zero S (9 iters) + FW (144 uint4 units)
        uint4 z = make_uint4(0,0,0,0);
        uint4* Sv = (uint4*)S;
#pragma unroll
        for (int i = 0; i < 9; ++i) Sv[l + 64*i] = z;
        uint4* Fv = (uint4*)FW;
#pragma unroll
        for (int i = 0; i < 3; ++i) {
            int idx = l + 64*i;
            if (idx < (16*SP*2)/16) Fv[idx] = z;
        }
    }
    size_t t = (size_t)n * KNBR + l;
    ushort4 gp = geomF[t];
    int cell = geomI[t];
    int j = nbr[t];
    {
        float win = bf2f(gp.x);
        float x1 = bf2f(gp.y), y1 = bf2f(gp.z), z1 = bf2f(gp.w);
        float x0 = 1.f-x1, y0 = 1.f-y1, z0 = 1.f-z1;
        float w00 = y0*z0*win, w01 = y0*z1*win, w10 = y1*z0*win, w11 = y1*z1*win;
        ushort* Sc = S + cell*SP + l;
        Sc[0*SP]  = f2bf(x0*w00);
        Sc[1*SP]  = f2bf(x0*w01);
        Sc[4*SP]  = f2bf(x0*w10);
        Sc[5*SP]  = f2bf(x0*w11);
        Sc[16*SP] = f2bf(x1*w00);
        Sc[17*SP] = f2bf(x1*w01);
        Sc[20*SP] = f2bf(x1*w10);
        Sc[21*SP] = f2bf(x1*w11);
    }
    {   // FW rows 0..2 = neighbor features
        const float* fr = feat + (size_t)j * 3;
        FW[0*SP + l] = f2bf(fr[0]);
        FW[1*SP + l] = f2bf(fr[1]);
        FW[2*SP + l] = f2bf(fr[2]);
    }
    int lm = l & 15, koct = l >> 4;
    f32x4 acc[4];
#pragma unroll
    for (int mt = 0; mt < 4; ++mt) acc[mt] = (f32x4){0.f,0.f,0.f,0.f};
#pragma unroll
    for (int ks = 0; ks < 2; ++ks) {
        bf16x8 ff = *(const bf16x8*)&FW[lm*SP + ks*32 + koct*8];
#pragma unroll
        for (int mt = 0; mt < 4; ++mt) {
            bf16x8 sf = *(const bf16x8*)&S[(mt*16 + lm)*SP + ks*32 + koct*8];
            acc[mt] = __builtin_amdgcn_mfma_f32_16x16x32_bf16(sf, ff, acc[mt], 0, 0, 0);
        }
    }
    ushort* AT = FW;
    if (lm < 3) {
#pragma unroll
        for (int mt = 0; mt < 4; ++mt) {
            u16x4 pk;
            pk.x = f2bf(acc[mt][0]);
            pk.y = f2bf(acc[mt][1]);
            pk.z = f2bf(acc[mt][2]);
            pk.w = f2bf(acc[mt][3]);
            *(u16x4*)&AT[lm*SP + mt*16 + koct*4] = pk;
        }
    }
    ushort* Arow = A + (size_t)n * Ktot;
    if (l < 24) {
        int ch = l >> 3, cc = (l & 7) * 8;
        *(uint4*)&Arow[ch*64 + cc] = *(const uint4*)&AT[ch*SP + cc];
    }
}

// dense_1 = fluid_vel @ W_d1 + b_d1 -> out1b columns [64..96) (bf16)
__global__ void dense1_kernel(const float* __restrict__ vel,
                              const float* __restrict__ Wd,
                              const float* __restrict__ bd,
                              ushort* __restrict__ out1b, int M) {
    int t = blockIdx.x * blockDim.x + threadIdx.x;
    if (t >= M*32) return;
    int n = t >> 5, c = t & 31;
    float v = bd[c] + vel[n*3+0]*Wd[c] + vel[n*3+1]*Wd[32+c] + vel[n*3+2]*Wd[64+c];
    out1b[(size_t)n*96 + 64 + c] = f2bf(v);
}

// ---- merged weight prep: all 5 transposes in one launch.
__device__ __forceinline__ void wprep_one(const float* Wc, int Kc,
                                          const float* Wd, int N,
                                          ushort* Wt, int Ktot, int t) {
    int nn = t / Ktot, k = t - nn * Ktot;
    float v;
    if (k < Kc) {
        int cinl = Kc >> 6;
        int ch = k >> 6, cl = k & 63;
        v = Wc[(size_t)(cl*cinl + ch)*N + nn];
    } else {
        v = Wd[(size_t)(k-Kc)*N + nn];
    }
    Wt[(size_t)nn*Ktot + k] = f2bf(v);
}

__global__ void wprep_all_kernel(
        const float* __restrict__ W_wall1, const float* __restrict__ W_fluid1,
        const float* __restrict__ W_c2, const float* __restrict__ W_d2,
        const float* __restrict__ W_c3, const float* __restrict__ W_d3,
        const float* __restrict__ W_c4,
        ushort* __restrict__ Wt1a, ushort* __restrict__ Wt1b,
        ushort* __restrict__ Wt2, ushort* __restrict__ Wt3,
        ushort* __restrict__ Wt4) {
    int t = blockIdx.x * 256 + threadIdx.x;
    const int s0 = 32*192, s1 = s0 + 32*192, s2 = s1 + 64*6240,
              s3 = s2 + 64*4160, s4 = s3 + 192*64;
    if (t < s0) {
        wprep_one(W_wall1, 192, nullptr, 32, Wt1a, 192, t);
    } else if (t < s1) {
        wprep_one(W_fluid1, 192, nullptr, 32, Wt1b, 192, t - s0);
    } else if (t < s2) {
        wprep_one(W_c2, 6144, W_d2, 64, Wt2, 6240, t - s1);
    } else if (t < s3) {
        wprep_one(W_c3, 4096, W_d3, 64, Wt3, 4160, t - s2);
    } else if (t < s4) {
        int u = t - s3;
        int row = u >> 6, ch = u & 63;       // row = cell*3 + c
        int cell = row / 3, c = row - cell*3;
        Wt4[row*64 + ch] = f2bf(W_c4[(cell*64 + ch)*3 + c]);
    }
}

// ---- L1 GEMM, fused epilogue, both halves (blockIdx.y: 0=wall, 1=fluid).
__global__ __launch_bounds__(256) void gemm_l1_kernel(
        const ushort* __restrict__ A0, const ushort* __restrict__ A1,
        const ushort* __restrict__ Wt0, const ushort* __restrict__ Wt1,
        const float* __restrict__ b0, const float* __restrict__ b1,
        ushort* __restrict__ out1b, int M) {
    constexpr int Ktot = 192, nks = 6, NCT = 2;
    const ushort* A;  const ushort* Wt; const float* bias; int ocol;
    if (blockIdx.y == 0) { A = A0; Wt = Wt0; bias = b0; ocol = 0; }
    else                 { A = A1; Wt = Wt1; bias = b1; ocol = 32; }
    int tid = threadIdx.x;
    int w = tid >> 6, l = tid & 63;
    int lm = l & 15, koct = l >> 4;
    int mb = blockIdx.x;

    const ushort* Arow = A + (size_t)(mb*64 + w*16 + lm) * Ktot + koct*8;
    const ushort* Wrow = Wt + (size_t)lm * Ktot + koct*8;

    f32x4 acc[NCT];
#pragma unroll
    for (int ct = 0; ct < NCT; ++ct) acc[ct] = (f32x4){0.f,0.f,0.f,0.f};

    bf16x8 ac = *(const bf16x8*)(Arow);
    bf16x8 bc[NCT];
#pragma unroll
    for (int ct = 0; ct < NCT; ++ct)
        bc[ct] = *(const bf16x8*)(Wrow + (size_t)ct*16*Ktot);
#pragma unroll
    for (int ks = 0; ks < nks; ++ks) {
        bf16x8 an = {};
        bf16x8 bn[NCT] = {};
        if (ks + 1 < nks) {
            int k0 = (ks + 1) * 32;
            an = *(const bf16x8*)(Arow + k0);
#pragma unroll
            for (int ct = 0; ct < NCT; ++ct)
                bn[ct] = *(const bf16x8*)(Wrow + (size_t)ct*16*Ktot + k0);
        }
#pragma unroll
        for (int ct = 0; ct < NCT; ++ct)
            acc[ct] = __builtin_amdgcn_mfma_f32_16x16x32_bf16(ac, bc[ct], acc[ct], 0, 0, 0);
        ac = an;
#pragma unroll
        for (int ct = 0; ct < NCT; ++ct) bc[ct] = bn[ct];
    }

    int rbase = mb*64 + w*16 + koct*4;
#pragma unroll
    for (int ct = 0; ct < NCT; ++ct) {
        int col = ct*16 + lm;
        float bb = bias[col];
#pragma unroll
        for (int r = 0; r < 4; ++r) {
            float v = fmaxf(acc[ct][r] + bb, 0.f);
            out1b[(size_t)(rbase + r)*96 + ocol + col] = f2bf(v);
        }
    }
}

// GEMM v7 (layers 2/3, N=64): LDS-staged A+B, double-buffered, BK=32.
// Partial C stored bf16 (re-summed fp32 in reduce).
__global__ __launch_bounds__(256) void gemm7_kernel(
        const ushort* __restrict__ A, int Ktot,
        const ushort* __restrict__ Wt,
        ushort* __restrict__ Cpart, int rows, int nks, int KS) {
    constexpr int N = 64;
    constexpr int SP = 40;
    __shared__ ushort Ash[2][128][SP];
    __shared__ ushort Bsh[2][64][SP];
    int tid = threadIdx.x;
    int w = tid >> 6, l = tid & 63;
    int lm = l & 15, koct = l >> 4;
    int mb = blockIdx.x;
    int per = (nks + KS - 1) / KS;
    int ksa = blockIdx.y * per;
    int ksb = ksa + per; if (ksb > nks) ksb = nks;
    int nk = ksb - ksa;

    f32x4 acc[2][4];
#pragma unroll
    for (int fi = 0; fi < 2; ++fi)
#pragma unroll
        for (int nt = 0; nt < 4; ++nt) acc[fi][nt] = (f32x4){0.f,0.f,0.f,0.f};

    int rS  = tid >> 2;          // 0..63
    int kb4 = tid & 3;           // 16B unit within 64B row-chunk
    int rA0 = mb*128 + rS;       if (rA0 >= rows) rA0 = rows - 1;
    int rA1 = mb*128 + rS + 64;  if (rA1 >= rows) rA1 = rows - 1;

    bf16x8 ra0, ra1, rb;
    auto load_regs = [&](int ks) {
        int kk = ks*32 + kb4*8;
        ra0 = *(const bf16x8*)&A[(size_t)rA0*Ktot + kk];
        ra1 = *(const bf16x8*)&A[(size_t)rA1*Ktot + kk];
        rb  = *(const bf16x8*)&Wt[(size_t)rS*Ktot + kk];
    };
    auto store_lds = [&](int buf) {
        *(bf16x8*)&Ash[buf][rS][kb4*8]      = ra0;
        *(bf16x8*)&Ash[buf][rS + 64][kb4*8] = ra1;
        *(bf16x8*)&Bsh[buf][rS][kb4*8]      = rb;
    };

    if (nk > 0) {
        load_regs(ksa);
        store_lds(0);
        __syncthreads();
        for (int i = 0; i < nk; ++i) {
            int buf = i & 1;
            bool nxt = (i + 1 < nk);
            if (nxt) load_regs(ksa + i + 1);
            bf16x8 a0 = *(const bf16x8*)&Ash[buf][w*32 + lm][koct*8];
            bf16x8 a1 = *(const bf16x8*)&Ash[buf][w*32 + 16 + lm][koct*8];
#pragma unroll
            for (int nt = 0; nt < 4; ++nt) {
                bf16x8 b = *(const bf16x8*)&Bsh[buf][nt*16 + lm][koct*8];
                acc[0][nt] = __builtin_amdgcn_mfma_f32_16x16x32_bf16(a0, b, acc[0][nt], 0, 0, 0);
                acc[1][nt] = __builtin_amdgcn_mfma_f32_16x16x32_bf16(a1, b, acc[1][nt], 0, 0, 0);
            }
            if (nxt) {
                store_lds(buf ^ 1);
                __syncthreads();
            }
        }
    }

    ushort* Cp = Cpart + ((size_t)blockIdx.y * rows + mb*128 + w*32) * N;
    int gr0 = mb*128 + w*32;
#pragma unroll
    for (int fi = 0; fi < 2; ++fi)
#pragma unroll
        for (int nt = 0; nt < 4; ++nt)
#pragma unroll
            for (int r = 0; r < 4; ++r) {
                int row = fi*16 + koct*4 + r;
                if (gr0 + row < rows)
                    Cp[row * N + nt*16 + lm] = f2bf(acc[fi][nt][r]);
            }
}

// Sum KS bf16 partial slabs (fp32 acc) + bias (+b2) (+bf16 res) (+relu)
// -> bf16 shadow outb (no fp32 output kept).
__global__ __launch_bounds__(256) void reduce_kernel(
        const ushort* __restrict__ Cpart, int rows, int N, int KS,
        const float* __restrict__ b1, const float* __restrict__ b2,
        const ushort* __restrict__ resb,
        int m_base, int relu,
        ushort* __restrict__ outb) {
    int idx = blockIdx.x * 256 + threadIdx.x;
    int nq = N >> 2;
    if (idx >= rows * nq) return;
    int row = idx / nq;
    int c4 = (idx - row * nq) * 4;
    size_t slab = (size_t)rows * N;
    const ushort* p = Cpart + (size_t)row * N + c4;
    float s0 = 0.f, s1 = 0.f, s2 = 0.f, s3 = 0.f;
    for (int k = 0; k < KS; ++k) {
        u16x4 v = *(const u16x4*)(p + slab * k);
        s0 += bf2f(v.x); s1 += bf2f(v.y); s2 += bf2f(v.z); s3 += bf2f(v.w);
    }
    s0 += b1[c4+0]; s1 += b1[c4+1]; s2 += b1[c4+2]; s3 += b1[c4+3];
    if (b2) { s0 += b2[c4+0]; s1 += b2[c4+1]; s2 += b2[c4+2]; s3 += b2[c4+3]; }
    if (resb) {
        const ushort* rr = resb + (size_t)(m_base + row) * 64 + c4;
        s0 += bf2f(rr[0]); s1 += bf2f(rr[1]); s2 += bf2f(rr[2]); s3 += bf2f(rr[3]);
    }
    if (relu) {
        s0 = fmaxf(s0, 0.f); s1 = fmaxf(s1, 0.f);
        s2 = fmaxf(s2, 0.f); s3 = fmaxf(s3, 0.f);
    }
    u16x4 pk;
    pk.x = f2bf(s0); pk.y = f2bf(s1); pk.z = f2bf(s2); pk.w = f2bf(s3);
    *(u16x4*)&outb[(size_t)(m_base + row) * 64 + c4] = pk;
}

// ---- Layer 4: G[16000,192] (bf16) = out3b @ Wt4^T via bf16 MFMA.
__global__ __launch_bounds__(256) void g4_mfma_kernel(
        const ushort* __restrict__ out3b,   // [M][64] bf16
        const ushort* __restrict__ Wt4,     // [192][64] bf16
        ushort* __restrict__ G, int M) {
    constexpr int SP = 72;
    __shared__ ushort Bsh[192*SP];
    int tid = threadIdx.x;
    for (int u = tid; u < 192*8; u += 256) {       // 192 rows x 8x16B units
        int row = u >> 3, seg = u & 7;
        *(bf16x8*)&Bsh[row*SP + seg*8] = *(const bf16x8*)&Wt4[row*64 + seg*8];
    }
    __syncthreads();
    int w = tid >> 6, l = tid & 63;
    int lm = l & 15, koct = l >> 4;
    int row0 = blockIdx.x*64 + w*16;               // M=16000=250*64: in range
    const ushort* Arow = out3b + (size_t)(row0 + lm)*64 + koct*8;
    bf16x8 a0 = *(const bf16x8*)(Arow);
    bf16x8 a1 = *(const bf16x8*)(Arow + 32);
    f32x4 acc[12];
#pragma unroll
    for (int nt = 0; nt < 12; ++nt) acc[nt] = (f32x4){0.f,0.f,0.f,0.f};
#pragma unroll
    for (int nt = 0; nt < 12; ++nt) {
        bf16x8 b = *(const bf16x8*)&Bsh[(nt*16 + lm)*SP + koct*8];
        acc[nt] = __builtin_amdgcn_mfma_f32_16x16x32_bf16(a0, b, acc[nt], 0, 0, 0);
    }
#pragma unroll
    for (int nt = 0; nt < 12; ++nt) {
        bf16x8 b = *(const bf16x8*)&Bsh[(nt*16 + lm)*SP + 32 + koct*8];
        acc[nt] = __builtin_amdgcn_mfma_f32_16x16x32_bf16(a1, b, acc[nt], 0, 0, 0);
    }
#pragma unroll
    for (int nt = 0; nt < 12; ++nt)
#pragma unroll
        for (int r = 0; r < 4; ++r)
            G[(size_t)(row0 + koct*4 + r)*192 + nt*16 + lm] = f2bf(acc[nt][r]);
}

// out[n][c] = biases + dense + sum_k win * sum_{8 cells} tri_w * G[j_k][cell][c]
__global__ __launch_bounds__(256) void l4_scatter_kernel(
        const ushort* __restrict__ G,       // [M][64 cells][3] bf16
        const ushort4* __restrict__ geomF,
        const int*   __restrict__ geomI,
        const int*   __restrict__ nbr,
        const ushort* __restrict__ out3b,
        const float* __restrict__ Wd4,
        const float* __restrict__ b_c4, const float* __restrict__ b_d4,
        float* __restrict__ out, int M) {
    __shared__ float Wsh[192];
    int tid = threadIdx.x;
    if (tid < 192) Wsh[tid] = Wd4[tid];
    __syncthreads();
    int wv = tid >> 6, l = tid & 63;
    int n = blockIdx.x*4 + wv;
    if (n >= M) return;
    size_t t = (size_t)n * KNBR + l;
    ushort4 gp = geomF[t];
    int cell = geomI[t];
    int j = nbr[t];
    float a0 = 0.f, a1 = 0.f, a2 = 0.f;
    float win = bf2f(gp.x);
    if (win > 0.f) {
        float x1 = bf2f(gp.y), y1 = bf2f(gp.z), z1 = bf2f(gp.w);
        float x0 = 1.f-x1, y0 = 1.f-y1, z0 = 1.f-z1;
        float w[8] = {x0*y0*z0, x0*y0*z1, x0*y1*z0, x0*y1*z1,
                      x1*y0*z0, x1*y0*z1, x1*y1*z0, x1*y1*z1};
        const int co[8] = {0,1,4,5,16,17,20,21};
        const ushort* Gj = G + (size_t)j*192;
#pragma unroll
        for (int i = 0; i < 8; ++i) {
            const ushort* Gc = Gj + (cell + co[i])*3;
            float ww = win * w[i];
            a0 += ww*bf2f(Gc[0]); a1 += ww*bf2f(Gc[1]); a2 += ww*bf2f(Gc[2]);
        }
    }
    {   // dense tail (bf16 shadow)
        float v = bf2f(out3b[(size_t)n*64 + l]);
        a0 += v*Wsh[l*3+0]; a1 += v*Wsh[l*3+1]; a2 += v*Wsh[l*3+2];
    }
#pragma unroll
    for (int off = 32; off; off >>= 1) {
        a0 += __shfl_down(a0, off, 64);
        a1 += __shfl_down(a1, off, 64);
        a2 += __shfl_down(a2, off, 64);
    }
    if (l == 0) {
        out[n*3+0] = a0 + b_c4[0] + b_d4[0];
        out[n*3+1] = a1 + b_c4[1] + b_d4[1];
        out[n*3+2] = a2 + b_c4[2] + b_d4[2];
    }
}

extern "C" void kernel_launch(void* const* d_in, const int* in_sizes, int n_in,
                              void* d_out, int out_size, void* d_ws, size_t ws_size,
                              hipStream_t stream) {
    const float* fluid_pos = (const float*)d_in[0];
    const float* wall_pos  = (const float*)d_in[1];
    const float* fluid_vel = (const float*)d_in[2];
    const float* wall_nrm  = (const float*)d_in[3];
    const int*   nbr_wf    = (const int*)d_in[4];
    const int*   nbr_ff    = (const int*)d_in[6];
    const float* W_wall1   = (const float*)d_in[8];
    const float* b_wall1   = (const float*)d_in[9];
    const float* W_fluid1  = (const float*)d_in[10];
    const float* b_fluid1  = (const float*)d_in[11];
    const float* W_d1      = (const float*)d_in[12];
    const float* b_d1      = (const float*)d_in[13];
    const float* W_c2      = (const float*)d_in[14];
    const float* b_c2      = (const float*)d_in[15];
    const float* W_d2      = (const float*)d_in[16];
    const float* b_d2      = (const float*)d_in[17];
    const float* W_c3      = (const float*)d_in[18];
    const float* b_c3      = (const float*)d_in[19];
    const float* W_d3      = (const float*)d_in[20];
    const float* b_d3      = (const float*)d_in[21];
    const float* W_c4      = (const float*)d_in[22];
    const float* b_c4      = (const float*)d_in[23];
    const float* W_d4      = (const float*)d_in[24];
    const float* b_d4      = (const float*)d_in[25];

    const int M = M_FLUID;
    char* ws = (char*)d_ws;
    size_t off = 0;
    auto carve = [&](size_t bytes) {
        char* p = ws + off;
        off = (off + bytes + 255) & ~(size_t)255;
        return p;
    };
    ushort4* gF_ff = (ushort4*)carve((size_t)M*KNBR*8);
    int*     gI_ff = (int*)    carve((size_t)M*KNBR*4);
    ushort4* gF_wf = (ushort4*)carve((size_t)M*KNBR*8);
    int*     gI_wf = (int*)    carve((size_t)M*KNBR*4);
    ushort*  out1b = (ushort*) carve((size_t)M*96*2);
    ushort*  out2b = (ushort*) carve((size_t)M*64*2);
    ushort*  out3b = (ushort*) carve((size_t)M*64*2);
    ushort*  Gbuf  = (ushort*) carve((size_t)M*192*2);
    ushort*  Wt1a  = (ushort*) carve((size_t)32*192*2);
    ushort*  Wt1b  = (ushort*) carve((size_t)32*192*2);
    ushort*  Wt2   = (ushort*) carve((size_t)64*6240*2);
    ushort*  Wt3   = (ushort*) carve((size_t)64*4160*2);
    ushort*  Wt4   = (ushort*) carve((size_t)192*64*2);
    ushort*  Cpart = (ushort*) carve((size_t)8*M*64*2);   // KS=8 bf16 slabs
    ushort*  Abuf  = (ushort*)(ws + off);
    size_t availA = (ws_size > off) ? (ws_size - off) : 0;

    auto chunkR = [&](int Ktot) -> int {
        size_t r = availA / ((size_t)Ktot * 2);   // bf16 A
        if (r > (size_t)M) r = (size_t)M;
        r &= ~(size_t)127;
        if (r < 128) r = 128;
        return (int)r;
    };

    // ---- merged weight prep (1 dispatch; perm matches abuild k'=ch*64+cell)
    {
        int total = 2*32*192 + 64*6240 + 64*4160 + 192*64;
        wprep_all_kernel<<<(total + 255)/256, 256, 0, stream>>>(
            W_wall1, W_fluid1, W_c2, W_d2, W_c3, W_d3, W_c4,
            Wt1a, Wt1b, Wt2, Wt3, Wt4);
    }
    // ---- geometry, both neighbor lists (1 dispatch)
    {
        int total = M * KNBR, thr = 256;
        geom_dual_kernel<<<dim3((total + thr - 1)/thr, 2), thr, 0, stream>>>(
            fluid_pos, wall_pos, nbr_ff, nbr_wf, gF_ff, gI_ff, gF_wf, gI_wf, M);
    }
    dense1_kernel<<<(M*32 + 255)/256, 256, 0, stream>>>(fluid_vel, W_d1, b_d1, out1b, M);

    // ---- layer 1 (both convs): abuild (1 dispatch) + fused gemm (1 dispatch)
    {
        ushort* A0 = Abuf;
        ushort* A1 = Abuf + (size_t)M*192;
        abuild_s3_dual_kernel<<<dim3(M, 2), 64, 0, stream>>>(
            wall_nrm, fluid_vel, nbr_wf, nbr_ff,
            gF_wf, gI_wf, gF_ff, gI_ff, A0, A1, M);
        gemm_l1_kernel<<<dim3(M/64, 2), 256, 0, stream>>>(
            A0, A1, Wt1a, Wt1b, b_wall1, b_fluid1, out1b, M);
    }
    // ---- layer 2: cin=96 -> out2b (bf16)
    {
        int Ktot = 6240, nks = 195, KS = 8, R = chunkR(Ktot);
        for (int m0 = 0; m0 < M; m0 += R) {
            int rows = (M - m0 < R) ? (M - m0) : R;
            abuild_s_kernel<96><<<rows, 64, 0, stream>>>(
                out1b, nbr_ff, gF_ff, gI_ff, out1b, Abuf, m0, m0+rows, Ktot);
            gemm7_kernel<<<dim3((rows+127)/128, KS), 256, 0, stream>>>(
                Abuf, Ktot, Wt2, Cpart, rows, nks, KS);
            reduce_kernel<<<(rows*16 + 255)/256, 256, 0, stream>>>(
                Cpart, rows, 64, KS, b_c2, b_d2, nullptr,
                m0, 1, out2b);
        }
    }
    // ---- layer 3: cin=64, residual (bf16) -> out3b
    {
        int Ktot = 4160, nks = 130, KS = 8, R = chunkR(Ktot);
        for (int m0 = 0; m0 < M; m0 += R) {
            int rows = (M - m0 < R) ? (M - m0) : R;
            abuild_s_kernel<64><<<rows, 64, 0, stream>>>(
                out2b, nbr_ff, gF_ff, gI_ff, out2b, Abuf, m0, m0+rows, Ktot);
            gemm7_kernel<<<dim3((rows+127)/128, KS), 256, 0, stream>>>(
                Abuf, Ktot, Wt3, Cpart, rows, nks, KS);
            reduce_kernel<<<(rows*16 + 255)/256, 256, 0, stream>>>(
                Cpart, rows, 64, KS, b_c3, b_d3, out2b,
                m0, 1, out3b);
        }
    }
    // ---- layer 4 (cout=3): G via MFMA + per-pair gather
    g4_mfma_kernel<<<M/64, 256, 0, stream>>>(out3b, Wt4, Gbuf, M);
    l4_scatter_kernel<<<(M+3)/4, 256, 0, stream>>>(
        Gbuf, gF_ff, gI_ff, nbr_ff, out3b, W_d4, b_c4, b_d4, (float*)d_out, M);
}

// Round 15
// 322.514 us; speedup vs baseline: 1.3439x; 1.0076x over previous
//
#include <hip/hip_runtime.h>
#include <hip/hip_bf16.h>

// ---------------------------------------------------------------------------
// Net_19378892440061: ContinuousConv fluid network, Round 15.
// Changes vs Round 14:
//  - wprep_all + geom_dual + dense1 (independent prologue work) merged into
//    ONE prep_kernel via block-range dispatch: saves 2 launch boundaries and
//    overlaps the small kernels' tails. All math unchanged.
// Pipeline is end-to-end BW-bound: abuild/gemm phases measured at ~88% of
// the 6.3 TB/s achievable ceiling; remaining gap is serial launch chain.
// ---------------------------------------------------------------------------

#define M_FLUID 16000
#define KNBR 64

typedef __attribute__((ext_vector_type(8))) short bf16x8;
typedef __attribute__((ext_vector_type(4))) float f32x4;
typedef __attribute__((ext_vector_type(4))) unsigned short u16x4;

__device__ __forceinline__ ushort f2bf(float f) {
    __hip_bfloat16 h = __float2bfloat16(f);   // RNE
    return *(ushort*)&h;
}
__device__ __forceinline__ float bf2f(ushort u) {
    union { uint i; float f; } c; c.i = (uint)u << 16; return c.f;
}

__device__ __forceinline__ float sgnf(float v) {
    return (v > 0.f) ? 1.f : ((v < 0.f) ? -1.f : 0.f);
}

// Volume-preserving ball->cube map (matches reference _ball_to_cube, fp32).
__device__ __forceinline__ void ball_to_cube(float x, float y, float z,
                                             float& xc, float& yc, float& zc) {
    const float eps = 1e-12f;
    float sq  = x*x + y*y + z*z;
    float nrm = sqrtf(fmaxf(sq, eps));
    float rho = sqrtf(fmaxf(x*x + y*y, eps));
    bool  top = (1.25f*z*z > x*x + y*y);
    float s_top = sqrtf(3.0f*nrm/(nrm + fabsf(z)));
    float xs = top ? x*s_top : x*nrm/rho;
    float ys = top ? y*s_top : y*nrm/rho;
    float zs = top ? sgnf(z)*nrm : 1.5f*z;
    if (sq < eps) { xs = 0.f; ys = 0.f; zs = 0.f; }
    float rxy = sqrtf(fmaxf(xs*xs + ys*ys, eps));
    bool use_x = fabsf(ys) <= fabsf(xs);
    float dx = (use_x && fabsf(xs) > eps) ? xs : 1.0f;
    float dy = (!use_x && fabsf(ys) > eps) ? ys : 1.0f;
    const float c4pi = 1.2732395447351628f;  // 4/pi
    float xc_, yc_;
    if (use_x) {
        xc_ = sgnf(xs)*rxy;
        yc_ = sgnf(xs)*rxy*c4pi*atanf(ys/dx);
    } else {
        xc_ = sgnf(ys)*rxy*c4pi*atanf(xs/dy);
        yc_ = sgnf(ys)*rxy;
    }
    if (xs*xs + ys*ys < eps) { xc_ = 0.f; yc_ = 0.f; }
    xc = xc_; yc = yc_; zc = zs;
}

// ---- merged weight prep helper.
__device__ __forceinline__ void wprep_one(const float* Wc, int Kc,
                                          const float* Wd, int N,
                                          ushort* Wt, int Ktot, int t) {
    int nn = t / Ktot, k = t - nn * Ktot;
    float v;
    if (k < Kc) {
        int cinl = Kc >> 6;
        int ch = k >> 6, cl = k & 63;
        v = Wc[(size_t)(cl*cinl + ch)*N + nn];
    } else {
        v = Wd[(size_t)(k-Kc)*N + nn];
    }
    Wt[(size_t)nn*Ktot + k] = f2bf(v);
}

// ---- fused prologue: weight prep + geometry (both lists) + dense_1.
// Block ranges: [0,B_wprep) wprep, [B_wprep,B_wprep+B_geom) geom (fluid then
// wall halves), rest dense1. All independent.
__global__ __launch_bounds__(256) void prep_kernel(
        const float* __restrict__ W_wall1, const float* __restrict__ W_fluid1,
        const float* __restrict__ W_c2, const float* __restrict__ W_d2,
        const float* __restrict__ W_c3, const float* __restrict__ W_d3,
        const float* __restrict__ W_c4,
        ushort* __restrict__ Wt1a, ushort* __restrict__ Wt1b,
        ushort* __restrict__ Wt2, ushort* __restrict__ Wt3,
        ushort* __restrict__ Wt4,
        const float* __restrict__ fluid_pos, const float* __restrict__ wall_pos,
        const int* __restrict__ nbrF, const int* __restrict__ nbrW,
        ushort4* __restrict__ gFf, int* __restrict__ gIf,
        ushort4* __restrict__ gFw, int* __restrict__ gIw,
        const float* __restrict__ vel, const float* __restrict__ Wd,
        const float* __restrict__ bd, ushort* __restrict__ out1b,
        int M, int B_wprep, int B_geom) {
    int b = blockIdx.x;
    if (b < B_wprep) {
        int t = b*256 + threadIdx.x;
        const int s0 = 32*192, s1 = s0 + 32*192, s2 = s1 + 64*6240,
                  s3 = s2 + 64*4160, s4 = s3 + 192*64;
        if (t < s0) {
            wprep_one(W_wall1, 192, nullptr, 32, Wt1a, 192, t);
        } else if (t < s1) {
            wprep_one(W_fluid1, 192, nullptr, 32, Wt1b, 192, t - s0);
        } else if (t < s2) {
            wprep_one(W_c2, 6144, W_d2, 64, Wt2, 6240, t - s1);
        } else if (t < s3) {
            wprep_one(W_c3, 4096, W_d3, 64, Wt3, 4160, t - s2);
        } else if (t < s4) {
            int u = t - s3;
            int row = u >> 6, ch = u & 63;       // row = cell*3 + c
            int cell = row / 3, c = row - cell*3;
            Wt4[row*64 + ch] = f2bf(W_c4[(cell*64 + ch)*3 + c]);
        }
        return;
    }
    if (b < B_wprep + B_geom) {
        int idx = b - B_wprep;
        int half = B_geom >> 1;
        int listy = (idx >= half) ? 1 : 0;
        int t = (idx - listy*half)*256 + threadIdx.x;
        if (t >= M * KNBR) return;
        const float* pos_in; const int* nbr; ushort4* geomF; int* geomI; int excl_self;
        if (listy == 0) { pos_in = fluid_pos; nbr = nbrF; geomF = gFf; geomI = gIf; excl_self = 1; }
        else            { pos_in = wall_pos;  nbr = nbrW; geomF = gFw; geomI = gIw; excl_self = 0; }
        int n = t >> 6;
        int k = t & 63;
        int j = nbr[t];
        float px = fluid_pos[n*3+0], py = fluid_pos[n*3+1], pz = fluid_pos[n*3+2];
        float qx = pos_in[(size_t)j*3+0], qy = pos_in[(size_t)j*3+1], qz = pos_in[(size_t)j*3+2];
        float dx = qx - px, dy = qy - py, dz = qz - pz;

        bool valid;
        if (k == 0) {
            // reproduce numpy fp32 distance exactly (no FMA contraction)
#pragma clang fp contract(off)
            float d2f = dx*dx + dy*dy;
            d2f = d2f + dz*dz;
            double d2 = (double)d2f;
            const double RADIUS_D = 0.5*(6.0*1.5*0.025);  // 0.1125
            valid = d2 < RADIUS_D*RADIUS_D;
            if (excl_self) valid = valid && (d2 > 1e-18);
        } else {
            valid = (j != 0);  // ascending neighbor ids: 0 past slot 0 == padding
        }

        const float Rf = (float)(0.5*(6.0*1.5*0.025));
        float ux = dx / Rf, uy = dy / Rf, uz = dz / Rf;
        float r2 = ux*ux + uy*uy; r2 += uz*uz;
        float w1 = 1.f - r2;
        float win = fminf(fmaxf(w1*w1*w1, 0.f), 1.f);

        float bx, by, bz;
        ball_to_cube(ux, uy, uz, bx, by, bz);
        float cx = fminf(fmaxf((bx*0.5f + 0.5f)*3.f, 0.f), 3.f);
        float cy = fminf(fmaxf((by*0.5f + 0.5f)*3.f, 0.f), 3.f);
        float cz = fminf(fmaxf((bz*0.5f + 0.5f)*3.f, 0.f), 3.f);
        float ix = fminf(fmaxf(floorf(cx), 0.f), 2.f);
        float iy = fminf(fmaxf(floorf(cy), 0.f), 2.f);
        float iz = fminf(fmaxf(floorf(cz), 0.f), 2.f);
        float fx = cx - ix, fy = cy - iy, fz = cz - iz;
        int cell = ((int)ix*4 + (int)iy)*4 + (int)iz;

        ushort4 gp;
        gp.x = f2bf(valid ? win : 0.f);
        gp.y = f2bf(fx); gp.z = f2bf(fy); gp.w = f2bf(fz);
        geomF[t] = gp;
        geomI[t] = cell;
        return;
    }
    {   // dense_1 = fluid_vel @ W_d1 + b_d1 -> out1b[:, 64..96)
        int t = (b - B_wprep - B_geom)*256 + threadIdx.x;
        if (t >= M*32) return;
        int n = t >> 5, c = t & 31;
        float v = bd[c] + vel[n*3+0]*Wd[c] + vel[n*3+1]*Wd[32+c] + vel[n*3+2]*Wd[64+c];
        out1b[(size_t)n*96 + 64 + c] = f2bf(v);
    }
}

// ---- MFMA-scatter abuild for CIN in {64, 96}. One wave = one particle.
template<int CIN>
__global__ __launch_bounds__(64) void abuild_s_kernel(
        const ushort* __restrict__ feat,
        const int*   __restrict__ nbr,
        const ushort4* __restrict__ geomF,
        const int*   __restrict__ geomI,
        const ushort* __restrict__ dense,
        ushort* __restrict__ A,
        int m0, int m1, int Ktot) {
    constexpr int SP = 72;              // row stride (elems): 144B, 16B-aligned
    constexpr int NT = CIN / 16;        // 6 (cin96) or 4 (cin64)
    __shared__ ushort S[64*SP];
    __shared__ ushort FW[CIN*SP];
    int l = threadIdx.x;
    int n = m0 + blockIdx.x;
    if (n >= m1) return;

    // 1. zero S
    {
        uint4 z = make_uint4(0,0,0,0);
        uint4* Sv = (uint4*)S;
#pragma unroll
        for (int i = 0; i < (64*SP*2)/(16*64); ++i)   // 9 iters
            Sv[l + 64*i] = z;
    }
    // 2. geometry -> S scatter (lane l owns neighbor k=l; distinct columns)
    size_t t = (size_t)n * KNBR + l;
    ushort4 gp = geomF[t];
    int cell = geomI[t];
    int j = nbr[t];
    {
        float win = bf2f(gp.x);
        float x1 = bf2f(gp.y), y1 = bf2f(gp.z), z1 = bf2f(gp.w);
        float x0 = 1.f-x1, y0 = 1.f-y1, z0 = 1.f-z1;
        float w00 = y0*z0*win, w01 = y0*z1*win, w10 = y1*z0*win, w11 = y1*z1*win;
        ushort* Sc = S + cell*SP + l;
        Sc[0*SP]  = f2bf(x0*w00);
        Sc[1*SP]  = f2bf(x0*w01);
        Sc[4*SP]  = f2bf(x0*w10);
        Sc[5*SP]  = f2bf(x0*w11);
        Sc[16*SP] = f2bf(x1*w00);
        Sc[17*SP] = f2bf(x1*w01);
        Sc[20*SP] = f2bf(x1*w10);
        Sc[21*SP] = f2bf(x1*w11);
    }
    // 3. FW build: lane l streams neighbor j's bf16 feature row -> FW[ch][l]
    {
        const ushort* frow = feat + (size_t)j * CIN;
#pragma unroll
        for (int c8 = 0; c8 < CIN; c8 += 8) {
            bf16x8 v = *(const bf16x8*)(frow + c8);
#pragma unroll
            for (int i = 0; i < 8; ++i)
                FW[(c8+i)*SP + l] = (ushort)v[i];
        }
    }
    // 4. per-particle MFMA: A_t[cell,ch] = sum_k S[cell,k]*FW[ch,k]
    int lm = l & 15, koct = l >> 4;
    f32x4 acc[4][NT];
#pragma unroll
    for (int mt = 0; mt < 4; ++mt)
#pragma unroll
        for (int nt = 0; nt < NT; ++nt)
            acc[mt][nt] = (f32x4){0.f, 0.f, 0.f, 0.f};
#pragma unroll
    for (int ks = 0; ks < 2; ++ks) {
        bf16x8 sf[4];
#pragma unroll
        for (int mt = 0; mt < 4; ++mt)
            sf[mt] = *(const bf16x8*)&S[(mt*16 + lm)*SP + ks*32 + koct*8];
#pragma unroll
        for (int nt = 0; nt < NT; ++nt) {
            bf16x8 ff = *(const bf16x8*)&FW[(nt*16 + lm)*SP + ks*32 + koct*8];
#pragma unroll
            for (int mt = 0; mt < 4; ++mt)
                acc[mt][nt] = __builtin_amdgcn_mfma_f32_16x16x32_bf16(
                                  sf[mt], ff, acc[mt][nt], 0, 0, 0);
        }
    }
    // 5. C/D: col(=ch)=lane&15, row(=cell)=(lane>>4)*4+reg -> AT[ch][cell]
    ushort* AT = FW;
#pragma unroll
    for (int nt = 0; nt < NT; ++nt)
#pragma unroll
        for (int mt = 0; mt < 4; ++mt) {
            u16x4 pk;
            pk.x = f2bf(acc[mt][nt][0]);
            pk.y = f2bf(acc[mt][nt][1]);
            pk.z = f2bf(acc[mt][nt][2]);
            pk.w = f2bf(acc[mt][nt][3]);
            *(u16x4*)&AT[(nt*16 + lm)*SP + mt*16 + koct*4] = pk;
        }
    // 6. coalesced writeback, k' = ch*64 + cell
    ushort* Arow = A + (size_t)(n - m0) * Ktot;
#pragma unroll
    for (int it = 0; it < CIN/8; ++it) {
        int i = l + 64*it;
        int ch = i >> 3, cc = (i & 7) * 8;
        uint4 v = *(const uint4*)&AT[ch*SP + cc];
        *(uint4*)&Arow[(ch << 6) + cc] = v;
    }
    // 7. dense tail (bf16 shadow: direct copy)
#pragma unroll
    for (int c0 = 0; c0 < CIN; c0 += 64) {
        int ch = c0 + l;
        if (ch < CIN) Arow[64*CIN + ch] = dense[(size_t)n*CIN + ch];
    }
}

// ---- MFMA-scatter abuild for CIN=3, BOTH L1 convs in one launch.
__global__ __launch_bounds__(64) void abuild_s3_dual_kernel(
        const float* __restrict__ featW, const float* __restrict__ featF,
        const int*   __restrict__ nbrW,  const int*   __restrict__ nbrF,
        const ushort4* __restrict__ gFw, const int* __restrict__ gIw,
        const ushort4* __restrict__ gFf, const int* __restrict__ gIf,
        ushort* __restrict__ A0, ushort* __restrict__ A1, int M) {
    constexpr int SP = 72;
    constexpr int Ktot = 192;
    __shared__ ushort S[64*SP];
    __shared__ ushort FW[16*SP];
    const float* feat; const int* nbr; const ushort4* geomF; const int* geomI; ushort* A;
    if (blockIdx.y == 0) { feat = featW; nbr = nbrW; geomF = gFw; geomI = gIw; A = A0; }
    else                 { feat = featF; nbr = nbrF; geomF = gFf; geomI = gIf; A = A1; }
    int l = threadIdx.x;
    int n = blockIdx.x;
    if (n >= M) return;

    {   // zero S (9 iters) + FW (144 uint4 units)
        uint4 z = make_uint4(0,0,0,0);
        uint4* Sv = (uint4*)S;
#pragma unroll
        for (int i = 0; i < 9; ++i) Sv[l + 64*i] = z;
        uint4* Fv = (uint4*)FW;
#pragma unroll
        for (int i = 0; i < 3; ++i) {
            int idx = l + 64*i;
            if (idx < (16*SP*2)/16) Fv[idx] = z;
        }
    }
    size_t t = (size_t)n * KNBR + l;
    ushort4 gp = geomF[t];
    int cell = geomI[t];
    int j = nbr[t];
    {
        float win = bf2f(gp.x);
        float x1 = bf2f(gp.y), y1 = bf2f(gp.z), z1 = bf2f(gp.w);
        float x0 = 1.f-x1, y0 = 1.f-y1, z0 = 1.f-z1;
        float w00 = y0*z0*win, w01 = y0*z1*win, w10 = y1*z0*win, w11 = y1*z1*win;
        ushort* Sc = S + cell*SP + l;
        Sc[0*SP]  = f2bf(x0*w00);
        Sc[1*SP]  = f2bf(x0*w01);
        Sc[4*SP]  = f2bf(x0*w10);
        Sc[5*SP]  = f2bf(x0*w11);
        Sc[16*SP] = f2bf(x1*w00);
        Sc[17*SP] = f2bf(x1*w01);
        Sc[20*SP] = f2bf(x1*w10);
        Sc[21*SP] = f2bf(x1*w11);
    }
    {   // FW rows 0..2 = neighbor features
        const float* fr = feat + (size_t)j * 3;
        FW[0*SP + l] = f2bf(fr[0]);
        FW[1*SP + l] = f2bf(fr[1]);
        FW[2*SP + l] = f2bf(fr[2]);
    }
    int lm = l & 15, koct = l >> 4;
    f32x4 acc[4];
#pragma unroll
    for (int mt = 0; mt < 4; ++mt) acc[mt] = (f32x4){0.f,0.f,0.f,0.f};
#pragma unroll
    for (int ks = 0; ks < 2; ++ks) {
        bf16x8 ff = *(const bf16x8*)&FW[lm*SP + ks*32 + koct*8];
#pragma unroll
        for (int mt = 0; mt < 4; ++mt) {
            bf16x8 sf = *(const bf16x8*)&S[(mt*16 + lm)*SP + ks*32 + koct*8];
            acc[mt] = __builtin_amdgcn_mfma_f32_16x16x32_bf16(sf, ff, acc[mt], 0, 0, 0);
        }
    }
    ushort* AT = FW;
    if (lm < 3) {
#pragma unroll
        for (int mt = 0; mt < 4; ++mt) {
            u16x4 pk;
            pk.x = f2bf(acc[mt][0]);
            pk.y = f2bf(acc[mt][1]);
            pk.z = f2bf(acc[mt][2]);
            pk.w = f2bf(acc[mt][3]);
            *(u16x4*)&AT[lm*SP + mt*16 + koct*4] = pk;
        }
    }
    ushort* Arow = A + (size_t)n * Ktot;
    if (l < 24) {
        int ch = l >> 3, cc = (l & 7) * 8;
        *(uint4*)&Arow[ch*64 + cc] = *(const uint4*)&AT[ch*SP + cc];
    }
}

// ---- L1 GEMM, fused epilogue, both halves (blockIdx.y: 0=wall, 1=fluid).
__global__ __launch_bounds__(256) void gemm_l1_kernel(
        const ushort* __restrict__ A0, const ushort* __restrict__ A1,
        const ushort* __restrict__ Wt0, const ushort* __restrict__ Wt1,
        const float* __restrict__ b0, const float* __restrict__ b1,
        ushort* __restrict__ out1b, int M) {
    constexpr int Ktot = 192, nks = 6, NCT = 2;
    const ushort* A;  const ushort* Wt; const float* bias; int ocol;
    if (blockIdx.y == 0) { A = A0; Wt = Wt0; bias = b0; ocol = 0; }
    else                 { A = A1; Wt = Wt1; bias = b1; ocol = 32; }
    int tid = threadIdx.x;
    int w = tid >> 6, l = tid & 63;
    int lm = l & 15, koct = l >> 4;
    int mb = blockIdx.x;

    const ushort* Arow = A + (size_t)(mb*64 + w*16 + lm) * Ktot + koct*8;
    const ushort* Wrow = Wt + (size_t)lm * Ktot + koct*8;

    f32x4 acc[NCT];
#pragma unroll
    for (int ct = 0; ct < NCT; ++ct) acc[ct] = (f32x4){0.f,0.f,0.f,0.f};

    bf16x8 ac = *(const bf16x8*)(Arow);
    bf16x8 bc[NCT];
#pragma unroll
    for (int ct = 0; ct < NCT; ++ct)
        bc[ct] = *(const bf16x8*)(Wrow + (size_t)ct*16*Ktot);
#pragma unroll
    for (int ks = 0; ks < nks; ++ks) {
        bf16x8 an = {};
        bf16x8 bn[NCT] = {};
        if (ks + 1 < nks) {
            int k0 = (ks + 1) * 32;
            an = *(const bf16x8*)(Arow + k0);
#pragma unroll
            for (int ct = 0; ct < NCT; ++ct)
                bn[ct] = *(const bf16x8*)(Wrow + (size_t)ct*16*Ktot + k0);
        }
#pragma unroll
        for (int ct = 0; ct < NCT; ++ct)
            acc[ct] = __builtin_amdgcn_mfma_f32_16x16x32_bf16(ac, bc[ct], acc[ct], 0, 0, 0);
        ac = an;
#pragma unroll
        for (int ct = 0; ct < NCT; ++ct) bc[ct] = bn[ct];
    }

    int rbase = mb*64 + w*16 + koct*4;
#pragma unroll
    for (int ct = 0; ct < NCT; ++ct) {
        int col = ct*16 + lm;
        float bb = bias[col];
#pragma unroll
        for (int r = 0; r < 4; ++r) {
            float v = fmaxf(acc[ct][r] + bb, 0.f);
            out1b[(size_t)(rbase + r)*96 + ocol + col] = f2bf(v);
        }
    }
}

// GEMM v7 (layers 2/3, N=64): LDS-staged A+B, double-buffered, BK=32.
// Partial C stored bf16 (re-summed fp32 in reduce).
__global__ __launch_bounds__(256) void gemm7_kernel(
        const ushort* __restrict__ A, int Ktot,
        const ushort* __restrict__ Wt,
        ushort* __restrict__ Cpart, int rows, int nks, int KS) {
    constexpr int N = 64;
    constexpr int SP = 40;
    __shared__ ushort Ash[2][128][SP];
    __shared__ ushort Bsh[2][64][SP];
    int tid = threadIdx.x;
    int w = tid >> 6, l = tid & 63;
    int lm = l & 15, koct = l >> 4;
    int mb = blockIdx.x;
    int per = (nks + KS - 1) / KS;
    int ksa = blockIdx.y * per;
    int ksb = ksa + per; if (ksb > nks) ksb = nks;
    int nk = ksb - ksa;

    f32x4 acc[2][4];
#pragma unroll
    for (int fi = 0; fi < 2; ++fi)
#pragma unroll
        for (int nt = 0; nt < 4; ++nt) acc[fi][nt] = (f32x4){0.f,0.f,0.f,0.f};

    int rS  = tid >> 2;          // 0..63
    int kb4 = tid & 3;           // 16B unit within 64B row-chunk
    int rA0 = mb*128 + rS;       if (rA0 >= rows) rA0 = rows - 1;
    int rA1 = mb*128 + rS + 64;  if (rA1 >= rows) rA1 = rows - 1;

    bf16x8 ra0, ra1, rb;
    auto load_regs = [&](int ks) {
        int kk = ks*32 + kb4*8;
        ra0 = *(const bf16x8*)&A[(size_t)rA0*Ktot + kk];
        ra1 = *(const bf16x8*)&A[(size_t)rA1*Ktot + kk];
        rb  = *(const bf16x8*)&Wt[(size_t)rS*Ktot + kk];
    };
    auto store_lds = [&](int buf) {
        *(bf16x8*)&Ash[buf][rS][kb4*8]      = ra0;
        *(bf16x8*)&Ash[buf][rS + 64][kb4*8] = ra1;
        *(bf16x8*)&Bsh[buf][rS][kb4*8]      = rb;
    };

    if (nk > 0) {
        load_regs(ksa);
        store_lds(0);
        __syncthreads();
        for (int i = 0; i < nk; ++i) {
            int buf = i & 1;
            bool nxt = (i + 1 < nk);
            if (nxt) load_regs(ksa + i + 1);
            bf16x8 a0 = *(const bf16x8*)&Ash[buf][w*32 + lm][koct*8];
            bf16x8 a1 = *(const bf16x8*)&Ash[buf][w*32 + 16 + lm][koct*8];
#pragma unroll
            for (int nt = 0; nt < 4; ++nt) {
                bf16x8 b = *(const bf16x8*)&Bsh[buf][nt*16 + lm][koct*8];
                acc[0][nt] = __builtin_amdgcn_mfma_f32_16x16x32_bf16(a0, b, acc[0][nt], 0, 0, 0);
                acc[1][nt] = __builtin_amdgcn_mfma_f32_16x16x32_bf16(a1, b, acc[1][nt], 0, 0, 0);
            }
            if (nxt) {
                store_lds(buf ^ 1);
                __syncthreads();
            }
        }
    }

    ushort* Cp = Cpart + ((size_t)blockIdx.y * rows + mb*128 + w*32) * N;
    int gr0 = mb*128 + w*32;
#pragma unroll
    for (int fi = 0; fi < 2; ++fi)
#pragma unroll
        for (int nt = 0; nt < 4; ++nt)
#pragma unroll
            for (int r = 0; r < 4; ++r) {
                int row = fi*16 + koct*4 + r;
                if (gr0 + row < rows)
                    Cp[row * N + nt*16 + lm] = f2bf(acc[fi][nt][r]);
            }
}

// Sum KS bf16 partial slabs (fp32 acc) + bias (+b2) (+bf16 res) (+relu)
// -> bf16 shadow outb.
__global__ __launch_bounds__(256) void reduce_kernel(
        const ushort* __restrict__ Cpart, int rows, int N, int KS,
        const float* __restrict__ b1, const float* __restrict__ b2,
        const ushort* __restrict__ resb,
        int m_base, int relu,
        ushort* __restrict__ outb) {
    int idx = blockIdx.x * 256 + threadIdx.x;
    int nq = N >> 2;
    if (idx >= rows * nq) return;
    int row = idx / nq;
    int c4 = (idx - row * nq) * 4;
    size_t slab = (size_t)rows * N;
    const ushort* p = Cpart + (size_t)row * N + c4;
    float s0 = 0.f, s1 = 0.f, s2 = 0.f, s3 = 0.f;
    for (int k = 0; k < KS; ++k) {
        u16x4 v = *(const u16x4*)(p + slab * k);
        s0 += bf2f(v.x); s1 += bf2f(v.y); s2 += bf2f(v.z); s3 += bf2f(v.w);
    }
    s0 += b1[c4+0]; s1 += b1[c4+1]; s2 += b1[c4+2]; s3 += b1[c4+3];
    if (b2) { s0 += b2[c4+0]; s1 += b2[c4+1]; s2 += b2[c4+2]; s3 += b2[c4+3]; }
    if (resb) {
        const ushort* rr = resb + (size_t)(m_base + row) * 64 + c4;
        s0 += bf2f(rr[0]); s1 += bf2f(rr[1]); s2 += bf2f(rr[2]); s3 += bf2f(rr[3]);
    }
    if (relu) {
        s0 = fmaxf(s0, 0.f); s1 = fmaxf(s1, 0.f);
        s2 = fmaxf(s2, 0.f); s3 = fmaxf(s3, 0.f);
    }
    u16x4 pk;
    pk.x = f2bf(s0); pk.y = f2bf(s1); pk.z = f2bf(s2); pk.w = f2bf(s3);
    *(u16x4*)&outb[(size_t)(m_base + row) * 64 + c4] = pk;
}

// ---- Layer 4: G[16000,192] (bf16) = out3b @ Wt4^T via bf16 MFMA.
__global__ __launch_bounds__(256) void g4_mfma_kernel(
        const ushort* __restrict__ out3b,   // [M][64] bf16
        const ushort* __restrict__ Wt4,     // [192][64] bf16
        ushort* __restrict__ G, int M) {
    constexpr int SP = 72;
    __shared__ ushort Bsh[192*SP];
    int tid = threadIdx.x;
    for (int u = tid; u < 192*8; u += 256) {       // 192 rows x 8x16B units
        int row = u >> 3, seg = u & 7;
        *(bf16x8*)&Bsh[row*SP + seg*8] = *(const bf16x8*)&Wt4[row*64 + seg*8];
    }
    __syncthreads();
    int w = tid >> 6, l = tid & 63;
    int lm = l & 15, koct = l >> 4;
    int row0 = blockIdx.x*64 + w*16;               // M=16000=250*64: in range
    const ushort* Arow = out3b + (size_t)(row0 + lm)*64 + koct*8;
    bf16x8 a0 = *(const bf16x8*)(Arow);
    bf16x8 a1 = *(const bf16x8*)(Arow + 32);
    f32x4 acc[12];
#pragma unroll
    for (int nt = 0; nt < 12; ++nt) acc[nt] = (f32x4){0.f,0.f,0.f,0.f};
#pragma unroll
    for (int nt = 0; nt < 12; ++nt) {
        bf16x8 b = *(const bf16x8*)&Bsh[(nt*16 + lm)*SP + koct*8];
        acc[nt] = __builtin_amdgcn_mfma_f32_16x16x32_bf16(a0, b, acc[nt], 0, 0, 0);
    }
#pragma unroll
    for (int nt = 0; nt < 12; ++nt) {
        bf16x8 b = *(const bf16x8*)&Bsh[(nt*16 + lm)*SP + 32 + koct*8];
        acc[nt] = __builtin_amdgcn_mfma_f32_16x16x32_bf16(a1, b, acc[nt], 0, 0, 0);
    }
#pragma unroll
    for (int nt = 0; nt < 12; ++nt)
#pragma unroll
        for (int r = 0; r < 4; ++r)
            G[(size_t)(row0 + koct*4 + r)*192 + nt*16 + lm] = f2bf(acc[nt][r]);
}

// out[n][c] = biases + dense + sum_k win * sum_{8 cells} tri_w * G[j_k][cell][c]
__global__ __launch_bounds__(256) void l4_scatter_kernel(
        const ushort* __restrict__ G,       // [M][64 cells][3] bf16
        const ushort4* __restrict__ geomF,
        const int*   __restrict__ geomI,
        const int*   __restrict__ nbr,
        const ushort* __restrict__ out3b,
        const float* __restrict__ Wd4,
        const float* __restrict__ b_c4, const float* __restrict__ b_d4,
        float* __restrict__ out, int M) {
    __shared__ float Wsh[192];
    int tid = threadIdx.x;
    if (tid < 192) Wsh[tid] = Wd4[tid];
    __syncthreads();
    int wv = tid >> 6, l = tid & 63;
    int n = blockIdx.x*4 + wv;
    if (n >= M) return;
    size_t t = (size_t)n * KNBR + l;
    ushort4 gp = geomF[t];
    int cell = geomI[t];
    int j = nbr[t];
    float a0 = 0.f, a1 = 0.f, a2 = 0.f;
    float win = bf2f(gp.x);
    if (win > 0.f) {
        float x1 = bf2f(gp.y), y1 = bf2f(gp.z), z1 = bf2f(gp.w);
        float x0 = 1.f-x1, y0 = 1.f-y1, z0 = 1.f-z1;
        float w[8] = {x0*y0*z0, x0*y0*z1, x0*y1*z0, x0*y1*z1,
                      x1*y0*z0, x1*y0*z1, x1*y1*z0, x1*y1*z1};
        const int co[8] = {0,1,4,5,16,17,20,21};
        const ushort* Gj = G + (size_t)j*192;
#pragma unroll
        for (int i = 0; i < 8; ++i) {
            const ushort* Gc = Gj + (cell + co[i])*3;
            float ww = win * w[i];
            a0 += ww*bf2f(Gc[0]); a1 += ww*bf2f(Gc[1]); a2 += ww*bf2f(Gc[2]);
        }
    }
    {   // dense tail (bf16 shadow)
        float v = bf2f(out3b[(size_t)n*64 + l]);
        a0 += v*Wsh[l*3+0]; a1 += v*Wsh[l*3+1]; a2 += v*Wsh[l*3+2];
    }
#pragma unroll
    for (int off = 32; off; off >>= 1) {
        a0 += __shfl_down(a0, off, 64);
        a1 += __shfl_down(a1, off, 64);
        a2 += __shfl_down(a2, off, 64);
    }
    if (l == 0) {
        out[n*3+0] = a0 + b_c4[0] + b_d4[0];
        out[n*3+1] = a1 + b_c4[1] + b_d4[1];
        out[n*3+2] = a2 + b_c4[2] + b_d4[2];
    }
}

extern "C" void kernel_launch(void* const* d_in, const int* in_sizes, int n_in,
                              void* d_out, int out_size, void* d_ws, size_t ws_size,
                              hipStream_t stream) {
    const float* fluid_pos = (const float*)d_in[0];
    const float* wall_pos  = (const float*)d_in[1];
    const float* fluid_vel = (const float*)d_in[2];
    const float* wall_nrm  = (const float*)d_in[3];
    const int*   nbr_wf    = (const int*)d_in[4];
    const int*   nbr_ff    = (const int*)d_in[6];
    const float* W_wall1   = (const float*)d_in[8];
    const float* b_wall1   = (const float*)d_in[9];
    const float* W_fluid1  = (const float*)d_in[10];
    const float* b_fluid1  = (const float*)d_in[11];
    const float* W_d1      = (const float*)d_in[12];
    const float* b_d1      = (const float*)d_in[13];
    const float* W_c2      = (const float*)d_in[14];
    const float* b_c2      = (const float*)d_in[15];
    const float* W_d2      = (const float*)d_in[16];
    const float* b_d2      = (const float*)d_in[17];
    const float* W_c3      = (const float*)d_in[18];
    const float* b_c3      = (const float*)d_in[19];
    const float* W_d3      = (const float*)d_in[20];
    const float* b_d3      = (const float*)d_in[21];
    const float* W_c4      = (const float*)d_in[22];
    const float* b_c4      = (const float*)d_in[23];
    const float* W_d4      = (const float*)d_in[24];
    const float* b_d4      = (const float*)d_in[25];

    const int M = M_FLUID;
    char* ws = (char*)d_ws;
    size_t off = 0;
    auto carve = [&](size_t bytes) {
        char* p = ws + off;
        off = (off + bytes + 255) & ~(size_t)255;
        return p;
    };
    ushort4* gF_ff = (ushort4*)carve((size_t)M*KNBR*8);
    int*     gI_ff = (int*)    carve((size_t)M*KNBR*4);
    ushort4* gF_wf = (ushort4*)carve((size_t)M*KNBR*8);
    int*     gI_wf = (int*)    carve((size_t)M*KNBR*4);
    ushort*  out1b = (ushort*) carve((size_t)M*96*2);
    ushort*  out2b = (ushort*) carve((size_t)M*64*2);
    ushort*  out3b = (ushort*) carve((size_t)M*64*2);
    ushort*  Gbuf  = (ushort*) carve((size_t)M*192*2);
    ushort*  Wt1a  = (ushort*) carve((size_t)32*192*2);
    ushort*  Wt1b  = (ushort*) carve((size_t)32*192*2);
    ushort*  Wt2   = (ushort*) carve((size_t)64*6240*2);
    ushort*  Wt3   = (ushort*) carve((size_t)64*4160*2);
    ushort*  Wt4   = (ushort*) carve((size_t)192*64*2);
    ushort*  Cpart = (ushort*) carve((size_t)8*M*64*2);   // KS=8 bf16 slabs
    ushort*  Abuf  = (ushort*)(ws + off);
    size_t availA = (ws_size > off) ? (ws_size - off) : 0;

    auto chunkR = [&](int Ktot) -> int {
        size_t r = availA / ((size_t)Ktot * 2);   // bf16 A
        if (r > (size_t)M) r = (size_t)M;
        r &= ~(size_t)127;
        if (r < 128) r = 128;
        return (int)r;
    };

    // ---- fused prologue: weight prep + geometry (both lists) + dense_1
    {
        int totalW = 2*32*192 + 64*6240 + 64*4160 + 192*64;
        int B_wprep = (totalW + 255)/256;
        int B_geom  = 2 * ((M*KNBR + 255)/256);
        int B_dense = (M*32 + 255)/256;
        prep_kernel<<<B_wprep + B_geom + B_dense, 256, 0, stream>>>(
            W_wall1, W_fluid1, W_c2, W_d2, W_c3, W_d3, W_c4,
            Wt1a, Wt1b, Wt2, Wt3, Wt4,
            fluid_pos, wall_pos, nbr_ff, nbr_wf,
            gF_ff, gI_ff, gF_wf, gI_wf,
            fluid_vel, W_d1, b_d1, out1b,
            M, B_wprep, B_geom);
    }

    // ---- layer 1 (both convs): abuild (1 dispatch) + fused gemm (1 dispatch)
    {
        ushort* A0 = Abuf;
        ushort* A1 = Abuf + (size_t)M*192;
        abuild_s3_dual_kernel<<<dim3(M, 2), 64, 0, stream>>>(
            wall_nrm, fluid_vel, nbr_wf, nbr_ff,
            gF_wf, gI_wf, gF_ff, gI_ff, A0, A1, M);
        gemm_l1_kernel<<<dim3(M/64, 2), 256, 0, stream>>>(
            A0, A1, Wt1a, Wt1b, b_wall1, b_fluid1, out1b, M);
    }
    // ---- layer 2: cin=96 -> out2b (bf16)
    {
        int Ktot = 6240, nks = 195, KS = 8, R = chunkR(Ktot);
        for (int m0 = 0; m0 < M; m0 += R) {
            int rows = (M - m0 < R) ? (M - m0) : R;
            abuild_s_kernel<96><<<rows, 64, 0, stream>>>(
                out1b, nbr_ff, gF_ff, gI_ff, out1b, Abuf, m0, m0+rows, Ktot);
            gemm7_kernel<<<dim3((rows+127)/128, KS), 256, 0, stream>>>(
                Abuf, Ktot, Wt2, Cpart, rows, nks, KS);
            reduce_kernel<<<(rows*16 + 255)/256, 256, 0, stream>>>(
                Cpart, rows, 64, KS, b_c2, b_d2, nullptr,
                m0, 1, out2b);
        }
    }
    // ---- layer 3: cin=64, residual (bf16) -> out3b
    {
        int Ktot = 4160, nks = 130, KS = 8, R = chunkR(Ktot);
        for (int m0 = 0; m0 < M; m0 += R) {
            int rows = (M - m0 < R) ? (M - m0) : R;
            abuild_s_kernel<64><<<rows, 64, 0, stream>>>(
                out2b, nbr_ff, gF_ff, gI_ff, out2b, Abuf, m0, m0+rows, Ktot);
            gemm7_kernel<<<dim3((rows+127)/128, KS), 256, 0, stream>>>(
                Abuf, Ktot, Wt3, Cpart, rows, nks, KS);
            reduce_kernel<<<(rows*16 + 255)/256, 256, 0, stream>>>(
                Cpart, rows, 64, KS, b_c3, b_d3, out2b,
                m0, 1, out3b);
        }
    }
    // ---- layer 4 (cout=3): G via MFMA + per-pair gather
    g4_mfma_kernel<<<M/64, 256, 0, stream>>>(out3b, Wt4, Gbuf, M);
    l4_scatter_kernel<<<(M+3)/4, 256, 0, stream>>>(
        Gbuf, gF_ff, gI_ff, nbr_ff, out3b, W_d4, b_c4, b_d4, (float*)d_out, M);
}